// Round 1
// baseline (696.478 us; speedup 1.0000x reference)
//
#include <hip/hip_runtime.h>
#include <stdint.h>

// ============================================================
// Adaptive log-softmax NLL, MI355X gfx950.  Round 6.
// R5 counters: k_logit_frag (c2) 178us, FETCH 325MB = W2 re-read 8x
// because the 8 M-tile blocks of one col-group land on 8 different XCD
// L2s (round-robin dispatch).  Fixes:
//  (1) c1/c2/c3: new W-register-stationary kernel: wave holds its W cols
//      as MFMA B-frags in registers, streams ALL 1024 rows (64 m16 tiles)
//      -> W read exactly once from global.
//  (2) c0 (K=1024, W can't live in regs): XCD-aware block swizzle so the
//      8 M-tiles sharing W cols run on the SAME XCD -> L2 absorbs re-read.
// ============================================================

typedef __attribute__((ext_vector_type(8))) short short8;   // 8 bf16
typedef __attribute__((ext_vector_type(4))) float f32x4;

__device__ __forceinline__ float bf2f(unsigned short u) {
    union { unsigned int i; float f; } v; v.i = ((unsigned int)u) << 16; return v.f;
}
__device__ __forceinline__ unsigned short f2bf(float f) {
    union { float f; unsigned int i; } v; v.f = f;
    unsigned int u = v.i;
    return (unsigned short)((u + 0x7fffu + ((u >> 16) & 1u)) >> 16);  // RNE
}
__device__ __forceinline__ float wave_sum(float v) {
    v += __shfl_xor(v, 1, 64);  v += __shfl_xor(v, 2, 64);
    v += __shfl_xor(v, 4, 64);  v += __shfl_xor(v, 8, 64);
    v += __shfl_xor(v, 16, 64); v += __shfl_xor(v, 32, 64);
    return v;
}
// pack 8 fp32 -> 8 bf16 (truncation) via v_perm: dst16[0]=hi16(f0), dst16[1]=hi16(f1)
__device__ __forceinline__ short8 pack8(float4 a, float4 b) {
    union { int4 i; short8 s; } r;
    r.i.x = __builtin_amdgcn_perm(__float_as_uint(a.y), __float_as_uint(a.x), 0x07060302u);
    r.i.y = __builtin_amdgcn_perm(__float_as_uint(a.w), __float_as_uint(a.z), 0x07060302u);
    r.i.z = __builtin_amdgcn_perm(__float_as_uint(b.y), __float_as_uint(b.x), 0x07060302u);
    r.i.w = __builtin_amdgcn_perm(__float_as_uint(b.w), __float_as_uint(b.z), 0x07060302u);
    return r.s;
}

// ---------------- fp32 -> bf16 convert (row-major) ----------------
__global__ void k_conv_hidden(const float* __restrict__ src,
                              unsigned short* __restrict__ dst, int n4) {
    int i = blockIdx.x * blockDim.x + threadIdx.x;
    if (i < n4) {
        float4 v = ((const float4*)src)[i];
        ushort4 o;
        o.x = f2bf(v.x); o.y = f2bf(v.y); o.z = f2bf(v.z); o.w = f2bf(v.w);
        ((ushort4*)dst)[i] = o;
    }
}

// ---------------- transpose [K][N] fp32 -> [N][K] bf16 ----------------
__global__ void k_transpose_bf16(const float* __restrict__ src,
                                 unsigned short* __restrict__ dst,
                                 int K, int N) {
    __shared__ unsigned short tile[32][33];
    int k0 = blockIdx.y * 32, n0 = blockIdx.x * 32;
    int tx = threadIdx.x, ty = threadIdx.y;
#pragma unroll
    for (int j = 0; j < 4; ++j) {
        int k = k0 + ty + j * 8, n = n0 + tx;
        float v = (n < N) ? src[(size_t)k * N + n] : 0.f;
        tile[ty + j * 8][tx] = f2bf(v);
    }
    __syncthreads();
#pragma unroll
    for (int j = 0; j < 4; ++j) {
        int n = n0 + ty + j * 8, k = k0 + tx;
        if (n < N) dst[(size_t)n * K + k] = tile[tx][ty + j * 8];
    }
}

// ---------------- projection GEMM, fragment-major output ----------------
#define BM 128
#define BN 128
#define BK 64
#define LDT 72
template <int NK32O>
__global__ __launch_bounds__(256)
void k_gemm_fragout(const unsigned short* __restrict__ A, int lda,
                    const unsigned short* __restrict__ B, int ldb,
                    unsigned short* __restrict__ Cf,
                    int N, int K) {
    __shared__ unsigned short lsA[BM * LDT];
    __shared__ unsigned short lsB[BN * LDT];
    int tid = threadIdx.x;
    int mBase = blockIdx.x * BM, nBase = blockIdx.y * BN;
    int wid = tid >> 6, lane = tid & 63;
    int wr = wid >> 1, wc = wid & 1;
    int q = lane >> 4, ln = lane & 15;
    f32x4 acc[4][4] = {};

    for (int k0 = 0; k0 < K; k0 += BK) {
        __syncthreads();
        int ch = tid & 7;
#pragma unroll
        for (int p = 0; p < 4; ++p) {
            int r = p * 32 + (tid >> 3);
            *(uint4*)(&lsA[r * LDT + ch * 8]) =
                *(const uint4*)(A + (size_t)(mBase + r) * lda + k0 + ch * 8);
        }
#pragma unroll
        for (int p = 0; p < 4; ++p) {
            int r = p * 32 + (tid >> 3);
            uint4 v = {0u, 0u, 0u, 0u};
            if (nBase + r < N)
                v = *(const uint4*)(B + (size_t)(nBase + r) * ldb + k0 + ch * 8);
            *(uint4*)(&lsB[r * LDT + ch * 8]) = v;
        }
        __syncthreads();
#pragma unroll
        for (int ks = 0; ks < 2; ++ks) {
            short8 af[4], bfr[4];
#pragma unroll
            for (int mi = 0; mi < 4; ++mi)
                af[mi] = *(const short8*)(&lsA[(wr * 64 + mi * 16 + ln) * LDT + ks * 32 + q * 8]);
#pragma unroll
            for (int ni = 0; ni < 4; ++ni)
                bfr[ni] = *(const short8*)(&lsB[(wc * 64 + ni * 16 + ln) * LDT + ks * 32 + q * 8]);
#pragma unroll
            for (int mi = 0; mi < 4; ++mi)
#pragma unroll
                for (int ni = 0; ni < 4; ++ni)
                    acc[mi][ni] = __builtin_amdgcn_mfma_f32_16x16x32_bf16(
                        af[mi], bfr[ni], acc[mi][ni], 0, 0, 0);
        }
    }
#pragma unroll
    for (int ni = 0; ni < 4; ++ni) {
        int col = nBase + wc * 64 + ni * 16 + ln;
        if (col < N) {
            int k32 = col >> 5, qc = (col >> 3) & 3, j = col & 7;
#pragma unroll
            for (int mi = 0; mi < 4; ++mi) {
                int m16 = (mBase >> 4) + wr * 4 + mi;
                size_t base = ((size_t)m16 * NK32O + k32) * 512 + (size_t)qc * 128 + j;
#pragma unroll
                for (int r = 0; r < 4; ++r) {
                    int mrem = q * 4 + r;
                    Cf[base + mrem * 8] = f2bf(acc[mi][ni][r]);
                }
            }
        }
    }
}

// ---------------- c0: fragment-streaming logit, XCD-swizzled grid ----------------
// grid (8, By8) with By8 = ceil(By/8)*8.  flat = x + 8*y; remap so the 8
// M-tiles sharing one W col-group all have flat%8 equal -> same XCD L2.
template <int NK32, int KD>
__global__ __launch_bounds__(256)
void k_logit_frag(const unsigned short* __restrict__ Af,
                  const float* __restrict__ W,
                  const float* __restrict__ bias,
                  float* __restrict__ rowsum,
                  int vocab) {
    int f = blockIdx.x + (blockIdx.y << 3);
    int u = f & 63;
    int xb = u >> 3;                      // M-tile 0..7
    int yb = ((f >> 6) << 3) + (u & 7);   // col-group (same (u&7) => same XCD)
    if (yb * 128 >= vocab) return;        // padded tail

    int tid = threadIdx.x;
    int wid = tid >> 6, lane = tid & 63;
    int wr = wid >> 1, wc = wid & 1;
    int q = lane >> 4, ln = lane & 15;
    int mb = xb * 128 + wr * 64;
    int nb = yb * 128 + wc * 64;
    int m16b = mb >> 4;

    const unsigned short* Abase = Af + (size_t)m16b * NK32 * 512 + lane * 8;
    const float* Wrow[4];
    bool nv[4];
#pragma unroll
    for (int ni = 0; ni < 4; ++ni) {
        int n = nb + ni * 16 + ln;
        nv[ni] = n < vocab;
        Wrow[ni] = W + (size_t)(nv[ni] ? n : 0) * KD + q * 8;
    }

    f32x4 acc[4][4] = {};
#pragma unroll 4
    for (int ks = 0; ks < NK32; ++ks) {
        short8 af[4];
#pragma unroll
        for (int mi = 0; mi < 4; ++mi)
            af[mi] = *(const short8*)(Abase + ((size_t)mi * NK32 + ks) * 512);
        short8 wf[4];
#pragma unroll
        for (int ni = 0; ni < 4; ++ni) {
            float4 a = {0.f, 0.f, 0.f, 0.f}, b = {0.f, 0.f, 0.f, 0.f};
            if (nv[ni]) {
                a = *(const float4*)(Wrow[ni] + ks * 32);
                b = *(const float4*)(Wrow[ni] + ks * 32 + 4);
            }
            wf[ni] = pack8(a, b);
        }
#pragma unroll
        for (int mi = 0; mi < 4; ++mi)
#pragma unroll
            for (int ni = 0; ni < 4; ++ni)
                acc[mi][ni] = __builtin_amdgcn_mfma_f32_16x16x32_bf16(
                    af[mi], wf[ni], acc[mi][ni], 0, 0, 0);
    }

    float s[4][4];
#pragma unroll
    for (int mi = 0; mi < 4; ++mi)
#pragma unroll
        for (int r = 0; r < 4; ++r) s[mi][r] = 0.f;
#pragma unroll
    for (int ni = 0; ni < 4; ++ni) {
        int col = nb + ni * 16 + ln;
        bool valid = col < vocab;
        float b = valid ? bias[col] : 0.f;
#pragma unroll
        for (int mi = 0; mi < 4; ++mi)
#pragma unroll
            for (int r = 0; r < 4; ++r)
                s[mi][r] += valid ? __expf(acc[mi][ni][r] + b) : 0.f;
    }
#pragma unroll
    for (int mi = 0; mi < 4; ++mi)
#pragma unroll
        for (int r = 0; r < 4; ++r) {
            float v = s[mi][r];
            v += __shfl_xor(v, 1, 64);
            v += __shfl_xor(v, 2, 64);
            v += __shfl_xor(v, 4, 64);
            v += __shfl_xor(v, 8, 64);
            s[mi][r] = v;
        }
    int sl = yb & 31;
    if (ln == 0) {
#pragma unroll
        for (int mi = 0; mi < 4; ++mi)
#pragma unroll
            for (int r = 0; r < 4; ++r)
                atomicAdd(&rowsum[sl * 1024 + mb + mi * 16 + q * 4 + r], s[mi][r]);
    }
}

// ---------------- c1/c2/c3: W-register-stationary, stream all M ----------------
// Wave owns NI*16 cols; loads W B-frags ONCE into registers, then streams
// MCHUNK m16 row-tiles (A frags from L2-resident h_if, double-buffered).
// grid (MSPLIT, ceil(vocab/(4*NI*16))), block 256 = 4 waves on distinct cols.
template <int NK32, int KD, int NI, int MCHUNK>
__global__ __launch_bounds__(256)
void k_logit_wstat(const unsigned short* __restrict__ Af,
                   const float* __restrict__ W,
                   const float* __restrict__ bias,
                   float* __restrict__ rowsum,
                   int vocab) {
    constexpr bool KGUARD = (NK32 * 32 != KD);   // only c3 (KD=16, padded K=32)
    int tid = threadIdx.x;
    int wid = tid >> 6, lane = tid & 63;
    int q = lane >> 4, ln = lane & 15;
    int nb = (blockIdx.y * 4 + wid) * (NI * 16);
    int m16_0 = blockIdx.x * MCHUNK;

    bool nv[NI];
    float bia[NI];
    short8 wf[NI][NK32];
#pragma unroll
    for (int ni = 0; ni < NI; ++ni) {
        int n = nb + ni * 16 + ln;
        nv[ni] = n < vocab;
        bia[ni] = nv[ni] ? bias[n] : 0.f;
        const float* wr = W + (size_t)(nv[ni] ? n : 0) * KD + q * 8;
#pragma unroll
        for (int ks = 0; ks < NK32; ++ks) {
            float4 a = {0.f, 0.f, 0.f, 0.f}, b = {0.f, 0.f, 0.f, 0.f};
            if (nv[ni] && (!KGUARD || q * 8 < KD)) {
                a = *(const float4*)(wr + ks * 32);
                b = *(const float4*)(wr + ks * 32 + 4);
            }
            wf[ni][ks] = pack8(a, b);
        }
    }

    int sl = blockIdx.y & 31;
    const unsigned short* Ab = Af + lane * 8;
    short8 af[NK32];
#pragma unroll
    for (int ks = 0; ks < NK32; ++ks)
        af[ks] = *(const short8*)(Ab + ((size_t)m16_0 * NK32 + ks) * 512);

    for (int m16 = m16_0; m16 < m16_0 + MCHUNK; ++m16) {
        f32x4 acc[NI] = {};
#pragma unroll
        for (int ks = 0; ks < NK32; ++ks)
#pragma unroll
            for (int ni = 0; ni < NI; ++ni)
                acc[ni] = __builtin_amdgcn_mfma_f32_16x16x32_bf16(
                    af[ks], wf[ni][ks], acc[ni], 0, 0, 0);
        if (m16 + 1 < m16_0 + MCHUNK) {       // prefetch next A tile
#pragma unroll
            for (int ks = 0; ks < NK32; ++ks)
                af[ks] = *(const short8*)(Ab + ((size_t)(m16 + 1) * NK32 + ks) * 512);
        }
        float s[4] = {0.f, 0.f, 0.f, 0.f};
#pragma unroll
        for (int ni = 0; ni < NI; ++ni) {
            bool v = nv[ni];
#pragma unroll
            for (int r = 0; r < 4; ++r)
                s[r] += v ? __expf(acc[ni][r] + bia[ni]) : 0.f;
        }
#pragma unroll
        for (int r = 0; r < 4; ++r) {
            float v = s[r];
            v += __shfl_xor(v, 1, 64);
            v += __shfl_xor(v, 2, 64);
            v += __shfl_xor(v, 4, 64);
            v += __shfl_xor(v, 8, 64);
            s[r] = v;
        }
        if (ln == 0) {
#pragma unroll
            for (int r = 0; r < 4; ++r)
                atomicAdd(&rowsum[sl * 1024 + m16 * 16 + q * 4 + r], s[r]);
        }
    }
}

// ---------------- fragment-major dot helper (per-wave) ----------------
__device__ __forceinline__ float frag_dot(const unsigned short* __restrict__ hf,
                                          int NK32, int KdReal, int n,
                                          const float* __restrict__ wrow, int lane) {
    float s = 0.f;
    for (int c = lane; c * 8 < KdReal; c += 64) {
        int k32 = c >> 2, qq = c & 3;
        const unsigned short* p = hf + ((size_t)(n >> 4) * NK32 + k32) * 512 + (qq * 16 + (n & 15)) * 8;
#pragma unroll
        for (int j = 0; j < 8; ++j)
            s += bf2f(p[j]) * wrow[c * 8 + j];
    }
    return wave_sum(s);
}

// ---------------- gather: per-token target logits + cluster logits ----------------
__global__ void k_gather(const unsigned short* __restrict__ h0f,
                         const unsigned short* __restrict__ h1f,
                         const unsigned short* __restrict__ h2f,
                         const unsigned short* __restrict__ h3f,
                         const float* __restrict__ W0, const float* __restrict__ b0,
                         const float* __restrict__ W1, const float* __restrict__ b1,
                         const float* __restrict__ W2, const float* __restrict__ b2,
                         const float* __restrict__ W3, const float* __restrict__ b3,
                         const float* __restrict__ cW, const float* __restrict__ cb,
                         const int* __restrict__ target,
                         float* __restrict__ rowsum0,
                         float* __restrict__ gat_head,
                         float* __restrict__ gat_tail) {
    int gw = (blockIdx.x * blockDim.x + threadIdx.x) >> 6;
    int lane = threadIdx.x & 63;
    if (gw >= 1024) return;
    int n = gw;
    int t = target[n];

    float cl[3];
#pragma unroll
    for (int j = 0; j < 3; ++j)
        cl[j] = frag_dot(h0f, 32, 1024, n, cW + j * 1024, lane) + cb[j];
    if (lane == 0)
        atomicAdd(&rowsum0[n], __expf(cl[0]) + __expf(cl[1]) + __expf(cl[2]));

    float gh, gt = 0.f;
    if (t < 20000) {
        gh = frag_dot(h0f, 32, 1024, n, W0 + (size_t)t * 1024, lane) + b0[t];
    } else {
        int c, l, Kd, NK32;
        const unsigned short* h; const float* W; const float* b;
        if (t < 40000)       { c = 1; l = 20000;  Kd = 256; NK32 = 8; h = h1f; W = W1; b = b1; }
        else if (t < 200000) { c = 2; l = 40000;  Kd = 64;  NK32 = 2; h = h2f; W = W2; b = b2; }
        else                 { c = 3; l = 200000; Kd = 16;  NK32 = 1; h = h3f; W = W3; b = b3; }
        gh = cl[3 - c];
        gt = frag_dot(h, NK32, Kd, n, W + (size_t)(t - l) * Kd, lane) + b[t - l];
    }
    if (lane == 0) { gat_head[n] = gh; gat_tail[n] = gt; }
}

// ---------------- finalize: sum slices, mean NLL ----------------
__global__ void k_finalize(const float* __restrict__ rs,  // [4][32][1024]
                           const float* __restrict__ gat_head,
                           const float* __restrict__ gat_tail,
                           const int* __restrict__ target,
                           float* __restrict__ out) {
    __shared__ float red[16];
    int n = threadIdx.x;
    int t = target[n];
    float r0 = 0.f;
#pragma unroll
    for (int s = 0; s < 32; ++s) r0 += rs[s * 1024 + n];
    float nll = __logf(r0) - gat_head[n];
    int c = (t < 20000) ? 0 : (t < 40000) ? 1 : (t < 200000) ? 2 : 3;
    if (c > 0) {
        float rc = 0.f;
#pragma unroll
        for (int s = 0; s < 32; ++s) rc += rs[c * 32768 + s * 1024 + n];
        nll += __logf(rc) - gat_tail[n];
    }
    float sm = wave_sum(nll);
    int wid = n >> 6, lane = n & 63;
    if (lane == 0) red[wid] = sm;
    __syncthreads();
    if (n == 0) {
        float tot = 0.f;
#pragma unroll
        for (int i = 0; i < 16; ++i) tot += red[i];
        out[0] = tot / 1024.0f;
    }
}

// ============================================================
extern "C" void kernel_launch(void* const* d_in, const int* in_sizes, int n_in,
                              void* d_out, int out_size, void* d_ws, size_t ws_size,
                              hipStream_t stream) {
    const float* hidden = (const float*)d_in[0];
    const int*   target = (const int*)d_in[1];
    const float* W0 = (const float*)d_in[2];
    const float* b0 = (const float*)d_in[3];
    const float* proj0 = (const float*)d_in[4];
    const float* W1 = (const float*)d_in[5];
    const float* b1 = (const float*)d_in[6];
    const float* proj1 = (const float*)d_in[7];
    const float* W2 = (const float*)d_in[8];
    const float* b2 = (const float*)d_in[9];
    const float* proj2 = (const float*)d_in[10];
    const float* W3 = (const float*)d_in[11];
    const float* b3 = (const float*)d_in[12];
    const float* proj3 = (const float*)d_in[13];
    const float* cW = (const float*)d_in[14];
    const float* cb = (const float*)d_in[15];

    char* ws = (char*)d_ws;
    unsigned short* hid_bf = (unsigned short*)(ws + 0x000000);  // 2 MB row-major bf16
    unsigned short* pT0 = (unsigned short*)(ws + 0x200000);     // 2 MB
    unsigned short* pT1 = (unsigned short*)(ws + 0x400000);     // 512 KB
    unsigned short* pT2 = (unsigned short*)(ws + 0x480000);     // 128 KB
    unsigned short* pT3 = (unsigned short*)(ws + 0x4A0000);     // 32 KB
    unsigned short* h0f = (unsigned short*)(ws + 0x4A8000);     // 2 MB   frag [64][32][64][8]
    unsigned short* h1f = (unsigned short*)(ws + 0x6A8000);     // 512 KB frag [64][8][64][8]
    unsigned short* h2f = (unsigned short*)(ws + 0x728000);     // 128 KB frag [64][2][64][8]
    unsigned short* h3f = (unsigned short*)(ws + 0x748000);     // 64 KB  frag [64][1][64][8] (K padded 16->32)
    float* rowsum   = (float*)(ws + 0x758000);                  // [4][32][1024] = 512 KB
    float* gat_head = (float*)(ws + 0x7D8000);                  // 4 KB
    float* gat_tail = (float*)(ws + 0x7D9000);                  // 4 KB

    hipMemsetAsync(ws + 0x748000, 0, 0x92000, stream);

    k_conv_hidden<<<1024, 256, 0, stream>>>(hidden, hid_bf, 1024 * 1024 / 4);

    dim3 tb(32, 8);
    k_transpose_bf16<<<dim3(32, 32), tb, 0, stream>>>(proj0, pT0, 1024, 1024);
    k_transpose_bf16<<<dim3(8, 32),  tb, 0, stream>>>(proj1, pT1, 1024, 256);
    k_transpose_bf16<<<dim3(2, 32),  tb, 0, stream>>>(proj2, pT2, 1024, 64);
    k_transpose_bf16<<<dim3(1, 32),  tb, 0, stream>>>(proj3, pT3, 1024, 16);

    k_gemm_fragout<32><<<dim3(8, 8), 256, 0, stream>>>(hid_bf, 1024, pT0, 1024, h0f, 1024, 1024);
    k_gemm_fragout<8> <<<dim3(8, 2), 256, 0, stream>>>(hid_bf, 1024, pT1, 1024, h1f, 256, 1024);
    k_gemm_fragout<2> <<<dim3(8, 1), 256, 0, stream>>>(hid_bf, 1024, pT2, 1024, h2f, 64, 1024);
    k_gemm_fragout<1> <<<dim3(8, 1), 256, 0, stream>>>(hid_bf, 1024, pT3, 1024, h3f, 16, 1024);

    // c0: XCD-swizzled fragment-streaming (grid y padded 157 -> 160)
    k_logit_frag<32, 1024><<<dim3(8, 160), 256, 0, stream>>>(h0f, W0, b0, rowsum + 0 * 32768, 20000);
    // c1: W-stationary, 128 cols/block, M split in 2 -> 314 blocks
    k_logit_wstat<8, 256, 2, 32><<<dim3(2, 157), 256, 0, stream>>>(h1f, W1, b1, rowsum + 1 * 32768, 20000);
    // c2: W-stationary, 256 cols/block, full M -> 625 blocks (W2 read ONCE)
    k_logit_wstat<2, 64, 4, 64><<<dim3(1, 625), 256, 0, stream>>>(h2f, W2, b2, rowsum + 2 * 32768, 160000);
    // c3: W-stationary, 256 cols/block -> 265 blocks
    k_logit_wstat<1, 16, 4, 64><<<dim3(1, 265), 256, 0, stream>>>(h3f, W3, b3, rowsum + 3 * 32768, 67735);

    k_gather<<<256, 256, 0, stream>>>(h0f, h1f, h2f, h3f, W0, b0, W1, b1, W2, b2, W3, b3,
                                      cW, cb, target, rowsum, gat_head, gat_tail);
    k_finalize<<<1, 1024, 0, stream>>>(rowsum, gat_head, gat_tail, target, (float*)d_out);
}

// Round 2
// 528.217 us; speedup vs baseline: 1.3185x; 1.3185x over previous
//
#include <hip/hip_runtime.h>
#include <stdint.h>

// ============================================================
// Adaptive log-softmax NLL, MI355X gfx950.  Round 7.
// R6 counters: c0 FETCH 325->60MB but dur unchanged 178us, MfmaUtil 9%
// -> latency-bound (Little's law: ~1.5KB/CU in flight = 3.8 TB/s cap).
// Total went UP: wstat per-m16 shfl epilogue is serial poison.
// Fixes:
//  (1) W pre-converted to bf16 B-frag-major (removes fp32 loads + v_perm
//      pack from all hot loops; halves W bytes).
//  (2) c0: explicit 2-buffer register pipeline, launch_bounds(256,3).
//  (3) c1/c2/c3: A-STATIONARY streamers: A-frags live in regs, W streams
//      through double-buffered frags, exp-sums accumulate in regs,
//      shuffle-reduce ONCE per block (not per 16 rows).
// ============================================================

typedef __attribute__((ext_vector_type(8))) short short8;   // 8 bf16
typedef __attribute__((ext_vector_type(4))) float f32x4;

__device__ __forceinline__ float bf2f(unsigned short u) {
    union { unsigned int i; float f; } v; v.i = ((unsigned int)u) << 16; return v.f;
}
__device__ __forceinline__ unsigned short f2bf(float f) {
    union { float f; unsigned int i; } v; v.f = f;
    unsigned int u = v.i;
    return (unsigned short)((u + 0x7fffu + ((u >> 16) & 1u)) >> 16);  // RNE
}
__device__ __forceinline__ float wave_sum(float v) {
    v += __shfl_xor(v, 1, 64);  v += __shfl_xor(v, 2, 64);
    v += __shfl_xor(v, 4, 64);  v += __shfl_xor(v, 8, 64);
    v += __shfl_xor(v, 16, 64); v += __shfl_xor(v, 32, 64);
    return v;
}
// pack 8 fp32 -> 8 bf16 (truncation) via v_perm
__device__ __forceinline__ short8 pack8(float4 a, float4 b) {
    union { int4 i; short8 s; } r;
    r.i.x = __builtin_amdgcn_perm(__float_as_uint(a.y), __float_as_uint(a.x), 0x07060302u);
    r.i.y = __builtin_amdgcn_perm(__float_as_uint(a.w), __float_as_uint(a.z), 0x07060302u);
    r.i.z = __builtin_amdgcn_perm(__float_as_uint(b.y), __float_as_uint(b.x), 0x07060302u);
    r.i.w = __builtin_amdgcn_perm(__float_as_uint(b.w), __float_as_uint(b.z), 0x07060302u);
    return r.s;
}

// ---------------- fp32 -> bf16 convert (row-major, hidden) ----------------
__global__ void k_conv_hidden(const float* __restrict__ src,
                              unsigned short* __restrict__ dst, int n4) {
    int i = blockIdx.x * blockDim.x + threadIdx.x;
    if (i < n4) {
        float4 v = ((const float4*)src)[i];
        ushort4 o;
        o.x = f2bf(v.x); o.y = f2bf(v.y); o.z = f2bf(v.z); o.w = f2bf(v.w);
        ((ushort4*)dst)[i] = o;
    }
}

// ---------------- W fp32 row-major -> bf16 B-frag-major ----------------
// Wf[u][ks][lane(q,ln)][j] = W[u*16+ln][ks*32+q*8+j]   (0 if OOB)
template <int NK32, int KD>
__global__ void k_conv_wfrag(const float* __restrict__ W,
                             unsigned short* __restrict__ Wf,
                             int vocab, int units) {
    int u = blockIdx.x * 4 + (threadIdx.x >> 6);
    if (u >= units) return;
    int lane = threadIdx.x & 63, q = lane >> 4, ln = lane & 15;
    int row = u * 16 + ln;
    bool rv = row < vocab;
    const float* src = W + (size_t)row * KD;
#pragma unroll
    for (int ks = 0; ks < NK32; ++ks) {
        int k0 = ks * 32 + q * 8;
        float4 a = {0.f, 0.f, 0.f, 0.f}, b = {0.f, 0.f, 0.f, 0.f};
        if (rv && k0 < KD) {
            a = *(const float4*)(src + k0);
            b = *(const float4*)(src + k0 + 4);
        }
        *(short8*)(Wf + ((size_t)u * NK32 + ks) * 512 + lane * 8) = pack8(a, b);
    }
}

// ---------------- transpose [K][N] fp32 -> [N][K] bf16 ----------------
__global__ void k_transpose_bf16(const float* __restrict__ src,
                                 unsigned short* __restrict__ dst,
                                 int K, int N) {
    __shared__ unsigned short tile[32][33];
    int k0 = blockIdx.y * 32, n0 = blockIdx.x * 32;
    int tx = threadIdx.x, ty = threadIdx.y;
#pragma unroll
    for (int j = 0; j < 4; ++j) {
        int k = k0 + ty + j * 8, n = n0 + tx;
        float v = (n < N) ? src[(size_t)k * N + n] : 0.f;
        tile[ty + j * 8][tx] = f2bf(v);
    }
    __syncthreads();
#pragma unroll
    for (int j = 0; j < 4; ++j) {
        int n = n0 + ty + j * 8, k = k0 + tx;
        if (n < N) dst[(size_t)n * K + k] = tile[tx][ty + j * 8];
    }
}

// ---------------- projection GEMM, fragment-major output ----------------
#define BM 128
#define BN 128
#define BK 64
#define LDT 72
template <int NK32O>
__global__ __launch_bounds__(256)
void k_gemm_fragout(const unsigned short* __restrict__ A, int lda,
                    const unsigned short* __restrict__ B, int ldb,
                    unsigned short* __restrict__ Cf,
                    int N, int K) {
    __shared__ unsigned short lsA[BM * LDT];
    __shared__ unsigned short lsB[BN * LDT];
    int tid = threadIdx.x;
    int mBase = blockIdx.x * BM, nBase = blockIdx.y * BN;
    int wid = tid >> 6, lane = tid & 63;
    int wr = wid >> 1, wc = wid & 1;
    int q = lane >> 4, ln = lane & 15;
    f32x4 acc[4][4] = {};

    for (int k0 = 0; k0 < K; k0 += BK) {
        __syncthreads();
        int ch = tid & 7;
#pragma unroll
        for (int p = 0; p < 4; ++p) {
            int r = p * 32 + (tid >> 3);
            *(uint4*)(&lsA[r * LDT + ch * 8]) =
                *(const uint4*)(A + (size_t)(mBase + r) * lda + k0 + ch * 8);
        }
#pragma unroll
        for (int p = 0; p < 4; ++p) {
            int r = p * 32 + (tid >> 3);
            uint4 v = {0u, 0u, 0u, 0u};
            if (nBase + r < N)
                v = *(const uint4*)(B + (size_t)(nBase + r) * ldb + k0 + ch * 8);
            *(uint4*)(&lsB[r * LDT + ch * 8]) = v;
        }
        __syncthreads();
#pragma unroll
        for (int ks = 0; ks < 2; ++ks) {
            short8 af[4], bfr[4];
#pragma unroll
            for (int mi = 0; mi < 4; ++mi)
                af[mi] = *(const short8*)(&lsA[(wr * 64 + mi * 16 + ln) * LDT + ks * 32 + q * 8]);
#pragma unroll
            for (int ni = 0; ni < 4; ++ni)
                bfr[ni] = *(const short8*)(&lsB[(wc * 64 + ni * 16 + ln) * LDT + ks * 32 + q * 8]);
#pragma unroll
            for (int mi = 0; mi < 4; ++mi)
#pragma unroll
                for (int ni = 0; ni < 4; ++ni)
                    acc[mi][ni] = __builtin_amdgcn_mfma_f32_16x16x32_bf16(
                        af[mi], bfr[ni], acc[mi][ni], 0, 0, 0);
        }
    }
#pragma unroll
    for (int ni = 0; ni < 4; ++ni) {
        int col = nBase + wc * 64 + ni * 16 + ln;
        if (col < N) {
            int k32 = col >> 5, qc = (col >> 3) & 3, j = col & 7;
#pragma unroll
            for (int mi = 0; mi < 4; ++mi) {
                int m16 = (mBase >> 4) + wr * 4 + mi;
                size_t base = ((size_t)m16 * NK32O + k32) * 512 + (size_t)qc * 128 + j;
#pragma unroll
                for (int r = 0; r < 4; ++r) {
                    int mrem = q * 4 + r;
                    Cf[base + mrem * 8] = f2bf(acc[mi][ni][r]);
                }
            }
        }
    }
}

// ---------------- c0: bf16-W fragment streaming, 2-stage reg pipeline ----------------
// grid (8, 160), XCD-swizzled so the 8 M-tiles of one col-group share an XCD.
__global__ __launch_bounds__(256, 3)
void k_head_exp(const unsigned short* __restrict__ Af,   // h0f [64][32][64][8]
                const unsigned short* __restrict__ Wf,   // W0f [1250][32][64][8]
                const float* __restrict__ bias,
                float* __restrict__ rowsum,
                int vocab) {
    int f = blockIdx.x + (blockIdx.y << 3);
    int u = f & 63;
    int xb = u >> 3;
    int yb = ((f >> 6) << 3) + (u & 7);
    if (yb * 128 >= vocab) return;

    int tid = threadIdx.x, wid = tid >> 6, lane = tid & 63;
    int wr = wid >> 1, wc = wid & 1;
    int q = lane >> 4, ln = lane & 15;
    int mb = xb * 128 + wr * 64;
    int nb = yb * 128 + wc * 64;
    int m16b = mb >> 4;
    int units = (vocab + 15) >> 4;

    const unsigned short* Ab = Af + (size_t)m16b * 32 * 512 + lane * 8;
    const unsigned short* Wp[4];
#pragma unroll
    for (int ni = 0; ni < 4; ++ni) {
        int un = (nb >> 4) + ni;
        Wp[ni] = Wf + (size_t)min(un, units - 1) * 32 * 512 + lane * 8;
    }

    f32x4 acc[4][4] = {};
    short8 a0[4], a1[4], w0[4], w1[4];
    auto LA = [&](short8* d, int kk) {
#pragma unroll
        for (int mi = 0; mi < 4; ++mi)
            d[mi] = *(const short8*)(Ab + ((size_t)mi * 32 + kk) * 512);
    };
    auto LW = [&](short8* d, int kk) {
#pragma unroll
        for (int ni = 0; ni < 4; ++ni)
            d[ni] = *(const short8*)(Wp[ni] + (size_t)kk * 512);
    };
    auto FM = [&](short8* a, short8* w) {
#pragma unroll
        for (int mi = 0; mi < 4; ++mi)
#pragma unroll
            for (int ni = 0; ni < 4; ++ni)
                acc[mi][ni] = __builtin_amdgcn_mfma_f32_16x16x32_bf16(
                    a[mi], w[ni], acc[mi][ni], 0, 0, 0);
    };

    LA(a0, 0); LW(w0, 0);
#pragma unroll
    for (int ks = 0; ks < 32; ks += 2) {
        LA(a1, ks + 1); LW(w1, ks + 1);
        FM(a0, w0);
        if (ks + 2 < 32) { LA(a0, ks + 2); LW(w0, ks + 2); }
        FM(a1, w1);
    }

    // epilogue: exp + bias, mask pad cols, reduce over 16 col-lanes, sliced atomics
    float s[4][4];
#pragma unroll
    for (int mi = 0; mi < 4; ++mi)
#pragma unroll
        for (int r = 0; r < 4; ++r) s[mi][r] = 0.f;
#pragma unroll
    for (int ni = 0; ni < 4; ++ni) {
        int col = nb + ni * 16 + ln;
        bool valid = col < vocab;
        float b = valid ? bias[col] : 0.f;
#pragma unroll
        for (int mi = 0; mi < 4; ++mi)
#pragma unroll
            for (int r = 0; r < 4; ++r)
                s[mi][r] += valid ? __expf(acc[mi][ni][r] + b) : 0.f;
    }
#pragma unroll
    for (int mi = 0; mi < 4; ++mi)
#pragma unroll
        for (int r = 0; r < 4; ++r) {
            float v = s[mi][r];
            v += __shfl_xor(v, 1, 64);
            v += __shfl_xor(v, 2, 64);
            v += __shfl_xor(v, 4, 64);
            v += __shfl_xor(v, 8, 64);
            s[mi][r] = v;
        }
    int sl = yb & 31;
    if (ln == 0) {
#pragma unroll
        for (int mi = 0; mi < 4; ++mi)
#pragma unroll
            for (int r = 0; r < 4; ++r)
                atomicAdd(&rowsum[sl * 1024 + mb + mi * 16 + q * 4 + r], s[mi][r]);
    }
}

// ---------------- c1/c2/c3: A-stationary streaming logit+exp ----------------
// Wave holds 64 rows x full K as A-frags in regs; streams W col-groups
// (16 cols each) with double-buffered W-frags; exp-sums accumulate in regs;
// shuffle-reduce + atomic ONCE per block.
// grid (CS, 4) with CS % 8 == 0 (same cols -> same XCD); block covers
// rows blockIdx.y*256..+255, col-units [x*ngroups, (x+1)*ngroups).
template <int NK32>
__global__ __launch_bounds__(256, 2)
void k_tail_exp(const unsigned short* __restrict__ Af,   // h_if [64][NK32][64][8]
                const unsigned short* __restrict__ Wf,   // bf16 frag [units][NK32][64][8]
                const float* __restrict__ bias,
                float* __restrict__ rowsum,
                int vocab, int units, int ngroups) {
    int tid = threadIdx.x;
    int wid = tid >> 6, lane = tid & 63;
    int q = lane >> 4, ln = lane & 15;
    int m16b = blockIdx.y * 16 + wid * 4;
    int u0 = blockIdx.x * ngroups;

    short8 af[4][NK32];
#pragma unroll
    for (int mi = 0; mi < 4; ++mi)
#pragma unroll
        for (int ks = 0; ks < NK32; ++ks)
            af[mi][ks] = *(const short8*)(Af + ((size_t)(m16b + mi) * NK32 + ks) * 512 + lane * 8);

    float rs[4][4];
#pragma unroll
    for (int mi = 0; mi < 4; ++mi)
#pragma unroll
        for (int r = 0; r < 4; ++r) rs[mi][r] = 0.f;

    const unsigned short* Wb = Wf + (size_t)lane * 8;
    auto LWG = [&](short8* d, int u) {
        int uc = min(u, units - 1);
#pragma unroll
        for (int ks = 0; ks < NK32; ++ks)
            d[ks] = *(const short8*)(Wb + ((size_t)uc * NK32 + ks) * 512);
    };
    auto CG = [&](short8* w, int u) {
        f32x4 acc[4] = {};
#pragma unroll
        for (int ks = 0; ks < NK32; ++ks)
#pragma unroll
            for (int mi = 0; mi < 4; ++mi)
                acc[mi] = __builtin_amdgcn_mfma_f32_16x16x32_bf16(
                    af[mi][ks], w[ks], acc[mi], 0, 0, 0);
        int col = u * 16 + ln;
        bool valid = col < vocab;
        float b = valid ? bias[col] : 0.f;
#pragma unroll
        for (int mi = 0; mi < 4; ++mi)
#pragma unroll
            for (int r = 0; r < 4; ++r)
                rs[mi][r] += valid ? __expf(acc[mi][r] + b) : 0.f;
    };

    short8 w0[NK32], w1[NK32];
    LWG(w0, u0);
    int g = 0;
    for (; g + 1 < ngroups; g += 2) {
        LWG(w1, u0 + g + 1);
        CG(w0, u0 + g);
        LWG(w0, u0 + g + 2);
        CG(w1, u0 + g + 1);
    }
    if (g < ngroups) CG(w0, u0 + g);

    int sl = blockIdx.x & 31;
#pragma unroll
    for (int mi = 0; mi < 4; ++mi)
#pragma unroll
        for (int r = 0; r < 4; ++r) {
            float v = rs[mi][r];
            v += __shfl_xor(v, 1, 64);
            v += __shfl_xor(v, 2, 64);
            v += __shfl_xor(v, 4, 64);
            v += __shfl_xor(v, 8, 64);
            if (ln == 0)
                atomicAdd(&rowsum[sl * 1024 + (m16b + mi) * 16 + q * 4 + r], v);
        }
}

// ---------------- fragment-major dot helper (per-wave) ----------------
__device__ __forceinline__ float frag_dot(const unsigned short* __restrict__ hf,
                                          int NK32, int KdReal, int n,
                                          const float* __restrict__ wrow, int lane) {
    float s = 0.f;
    for (int c = lane; c * 8 < KdReal; c += 64) {
        int k32 = c >> 2, qq = c & 3;
        const unsigned short* p = hf + ((size_t)(n >> 4) * NK32 + k32) * 512 + (qq * 16 + (n & 15)) * 8;
#pragma unroll
        for (int j = 0; j < 8; ++j)
            s += bf2f(p[j]) * wrow[c * 8 + j];
    }
    return wave_sum(s);
}

// ---------------- gather: per-token target logits + cluster logits ----------------
__global__ void k_gather(const unsigned short* __restrict__ h0f,
                         const unsigned short* __restrict__ h1f,
                         const unsigned short* __restrict__ h2f,
                         const unsigned short* __restrict__ h3f,
                         const float* __restrict__ W0, const float* __restrict__ b0,
                         const float* __restrict__ W1, const float* __restrict__ b1,
                         const float* __restrict__ W2, const float* __restrict__ b2,
                         const float* __restrict__ W3, const float* __restrict__ b3,
                         const float* __restrict__ cW, const float* __restrict__ cb,
                         const int* __restrict__ target,
                         float* __restrict__ rowsum0,
                         float* __restrict__ gat_head,
                         float* __restrict__ gat_tail) {
    int gw = (blockIdx.x * blockDim.x + threadIdx.x) >> 6;
    int lane = threadIdx.x & 63;
    if (gw >= 1024) return;
    int n = gw;
    int t = target[n];

    float cl[3];
#pragma unroll
    for (int j = 0; j < 3; ++j)
        cl[j] = frag_dot(h0f, 32, 1024, n, cW + j * 1024, lane) + cb[j];
    if (lane == 0)
        atomicAdd(&rowsum0[n], __expf(cl[0]) + __expf(cl[1]) + __expf(cl[2]));

    float gh, gt = 0.f;
    if (t < 20000) {
        gh = frag_dot(h0f, 32, 1024, n, W0 + (size_t)t * 1024, lane) + b0[t];
    } else {
        int c, l, Kd, NK32;
        const unsigned short* h; const float* W; const float* b;
        if (t < 40000)       { c = 1; l = 20000;  Kd = 256; NK32 = 8; h = h1f; W = W1; b = b1; }
        else if (t < 200000) { c = 2; l = 40000;  Kd = 64;  NK32 = 2; h = h2f; W = W2; b = b2; }
        else                 { c = 3; l = 200000; Kd = 16;  NK32 = 1; h = h3f; W = W3; b = b3; }
        gh = cl[3 - c];
        gt = frag_dot(h, NK32, Kd, n, W + (size_t)(t - l) * Kd, lane) + b[t - l];
    }
    if (lane == 0) { gat_head[n] = gh; gat_tail[n] = gt; }
}

// ---------------- finalize: sum slices, mean NLL ----------------
__global__ void k_finalize(const float* __restrict__ rs,  // [4][32][1024]
                           const float* __restrict__ gat_head,
                           const float* __restrict__ gat_tail,
                           const int* __restrict__ target,
                           float* __restrict__ out) {
    __shared__ float red[16];
    int n = threadIdx.x;
    int t = target[n];
    float r0 = 0.f;
#pragma unroll
    for (int s = 0; s < 32; ++s) r0 += rs[s * 1024 + n];
    float nll = __logf(r0) - gat_head[n];
    int c = (t < 20000) ? 0 : (t < 40000) ? 1 : (t < 200000) ? 2 : 3;
    if (c > 0) {
        float rc = 0.f;
#pragma unroll
        for (int s = 0; s < 32; ++s) rc += rs[c * 32768 + s * 1024 + n];
        nll += __logf(rc) - gat_tail[n];
    }
    float sm = wave_sum(nll);
    int wid = n >> 6, lane = n & 63;
    if (lane == 0) red[wid] = sm;
    __syncthreads();
    if (n == 0) {
        float tot = 0.f;
#pragma unroll
        for (int i = 0; i < 16; ++i) tot += red[i];
        out[0] = tot / 1024.0f;
    }
}

// ============================================================
extern "C" void kernel_launch(void* const* d_in, const int* in_sizes, int n_in,
                              void* d_out, int out_size, void* d_ws, size_t ws_size,
                              hipStream_t stream) {
    const float* hidden = (const float*)d_in[0];
    const int*   target = (const int*)d_in[1];
    const float* W0 = (const float*)d_in[2];
    const float* b0 = (const float*)d_in[3];
    const float* proj0 = (const float*)d_in[4];
    const float* W1 = (const float*)d_in[5];
    const float* b1 = (const float*)d_in[6];
    const float* proj1 = (const float*)d_in[7];
    const float* W2 = (const float*)d_in[8];
    const float* b2 = (const float*)d_in[9];
    const float* proj2 = (const float*)d_in[10];
    const float* W3 = (const float*)d_in[11];
    const float* b3 = (const float*)d_in[12];
    const float* proj3 = (const float*)d_in[13];
    const float* cW = (const float*)d_in[14];
    const float* cb = (const float*)d_in[15];

    char* ws = (char*)d_ws;
    unsigned short* hid_bf = (unsigned short*)(ws + 0x000000);  // 2 MB row-major bf16
    unsigned short* pT0 = (unsigned short*)(ws + 0x200000);     // 2 MB
    unsigned short* pT1 = (unsigned short*)(ws + 0x400000);     // 512 KB
    unsigned short* pT2 = (unsigned short*)(ws + 0x480000);     // 128 KB
    unsigned short* pT3 = (unsigned short*)(ws + 0x4A0000);     // 32 KB
    unsigned short* h0f = (unsigned short*)(ws + 0x4A8000);     // 2 MB   frag [64][32][64][8]
    unsigned short* h1f = (unsigned short*)(ws + 0x6A8000);     // 512 KB frag [64][8][64][8]
    unsigned short* h2f = (unsigned short*)(ws + 0x728000);     // 128 KB frag [64][2][64][8]
    unsigned short* h3f = (unsigned short*)(ws + 0x748000);     // 64 KB  frag [64][1][64][8] (K padded 16->32)
    float* rowsum   = (float*)(ws + 0x758000);                  // [4][32][1024] = 512 KB
    float* gat_head = (float*)(ws + 0x7D8000);                  // 4 KB
    float* gat_tail = (float*)(ws + 0x7D9000);                  // 4 KB
    // bf16 frag-major weights
    unsigned short* W0f = (unsigned short*)(ws + 0x00800000);   // 1250*32*1024 = 40.96 MB
    unsigned short* W1f = (unsigned short*)(ws + 0x02F10000);   // 1250*8*1024  = 10.24 MB
    unsigned short* W2f = (unsigned short*)(ws + 0x038D4000);   // 10000*2*1024 = 20.48 MB
    unsigned short* W3f = (unsigned short*)(ws + 0x04C5C000);   // 4234*1*1024  =  4.34 MB

    hipMemsetAsync(ws + 0x748000, 0, 0x92000, stream);

    k_conv_hidden<<<1024, 256, 0, stream>>>(hidden, hid_bf, 1024 * 1024 / 4);

    // W -> bf16 frag-major
    k_conv_wfrag<32, 1024><<<313,  256, 0, stream>>>(W0, W0f, 20000, 1250);
    k_conv_wfrag<8,  256> <<<313,  256, 0, stream>>>(W1, W1f, 20000, 1250);
    k_conv_wfrag<2,  64>  <<<2500, 256, 0, stream>>>(W2, W2f, 160000, 10000);
    k_conv_wfrag<1,  16>  <<<1059, 256, 0, stream>>>(W3, W3f, 67735, 4234);

    dim3 tb(32, 8);
    k_transpose_bf16<<<dim3(32, 32), tb, 0, stream>>>(proj0, pT0, 1024, 1024);
    k_transpose_bf16<<<dim3(8, 32),  tb, 0, stream>>>(proj1, pT1, 1024, 256);
    k_transpose_bf16<<<dim3(2, 32),  tb, 0, stream>>>(proj2, pT2, 1024, 64);
    k_transpose_bf16<<<dim3(1, 32),  tb, 0, stream>>>(proj3, pT3, 1024, 16);

    k_gemm_fragout<32><<<dim3(8, 8), 256, 0, stream>>>(hid_bf, 1024, pT0, 1024, h0f, 1024, 1024);
    k_gemm_fragout<8> <<<dim3(8, 2), 256, 0, stream>>>(hid_bf, 1024, pT1, 1024, h1f, 256, 1024);
    k_gemm_fragout<2> <<<dim3(8, 1), 256, 0, stream>>>(hid_bf, 1024, pT2, 1024, h2f, 64, 1024);
    k_gemm_fragout<1> <<<dim3(8, 1), 256, 0, stream>>>(hid_bf, 1024, pT3, 1024, h3f, 16, 1024);

    // c0: XCD-swizzled bf16 pipelined streamer
    k_head_exp<<<dim3(8, 160), 256, 0, stream>>>(h0f, W0f, b0, rowsum, 20000);
    // c1/c2/c3: A-stationary streamers (grid x % 8 == 0 -> col-sharing blocks on same XCD)
    k_tail_exp<8><<<dim3(64, 4),  256, 0, stream>>>(h1f, W1f, b1, rowsum + 1 * 32768, 20000, 1250, 20);
    k_tail_exp<2><<<dim3(160, 4), 256, 0, stream>>>(h2f, W2f, b2, rowsum + 2 * 32768, 160000, 10000, 63);
    k_tail_exp<1><<<dim3(128, 4), 256, 0, stream>>>(h3f, W3f, b3, rowsum + 3 * 32768, 67735, 4234, 34);

    k_gather<<<256, 256, 0, stream>>>(h0f, h1f, h2f, h3f, W0, b0, W1, b1, W2, b2, W3, b3,
                                      cW, cb, target, rowsum, gat_head, gat_tail);
    k_finalize<<<1, 1024, 0, stream>>>(rowsum, gat_head, gat_tail, target, (float*)d_out);
}

// Round 4
// 412.790 us; speedup vs baseline: 1.6872x; 1.2796x over previous
//
#include <hip/hip_runtime.h>
#include <stdint.h>

// ============================================================
// Adaptive log-softmax NLL, MI355X gfx950.  Round 9 (= R8 resubmit;
// R8 bench failed on container acquisition, no counters returned.
// Kernel re-audited: bounds/barriers/VGPR all clean).
// R7 counters: head 76us (MfmaUtil 22%) but total 528 -> ~450us is a
// long tail of 22 small serialized dispatches + gaps.  Structural fix:
// collapse 23 dispatches -> 4.
//  k_prep     : hidden conv + 4 W->bf16-frag converts + 4 transposes
//  k_gemm_all : 4 projection GEMMs (block-range dispatch)
//  k_logit_all: head + 3 tails + gather in ONE launch (head blocks
//               first; tails/gather backfill CUs -> overlap)
//  k_finalize
// Head inner loop: depth-3 rotating register pipeline (fully unrolled,
// static indices) to force ~16 outstanding loads per wave.
// ============================================================

typedef __attribute__((ext_vector_type(8))) short short8;   // 8 bf16
typedef __attribute__((ext_vector_type(4))) float f32x4;

__device__ __forceinline__ float bf2f(unsigned short u) {
    union { unsigned int i; float f; } v; v.i = ((unsigned int)u) << 16; return v.f;
}
__device__ __forceinline__ unsigned short f2bf(float f) {
    union { float f; unsigned int i; } v; v.f = f;
    unsigned int u = v.i;
    return (unsigned short)((u + 0x7fffu + ((u >> 16) & 1u)) >> 16);  // RNE
}
__device__ __forceinline__ float wave_sum(float v) {
    v += __shfl_xor(v, 1, 64);  v += __shfl_xor(v, 2, 64);
    v += __shfl_xor(v, 4, 64);  v += __shfl_xor(v, 8, 64);
    v += __shfl_xor(v, 16, 64); v += __shfl_xor(v, 32, 64);
    return v;
}
__device__ __forceinline__ short8 pack8(float4 a, float4 b) {
    union { int4 i; short8 s; } r;
    r.i.x = __builtin_amdgcn_perm(__float_as_uint(a.y), __float_as_uint(a.x), 0x07060302u);
    r.i.y = __builtin_amdgcn_perm(__float_as_uint(a.w), __float_as_uint(a.z), 0x07060302u);
    r.i.z = __builtin_amdgcn_perm(__float_as_uint(b.y), __float_as_uint(b.x), 0x07060302u);
    r.i.w = __builtin_amdgcn_perm(__float_as_uint(b.w), __float_as_uint(b.z), 0x07060302u);
    return r.s;
}

// ================= prep device functions =================
template <int NK32, int KD>
__device__ __forceinline__ void dev_convw(int bid, const float* __restrict__ W,
                                          unsigned short* __restrict__ Wf,
                                          int vocab, int units) {
    int u = bid * 4 + (threadIdx.x >> 6);
    if (u >= units) return;
    int lane = threadIdx.x & 63, q = lane >> 4, ln = lane & 15;
    int row = u * 16 + ln;
    bool rv = row < vocab;
    const float* src = W + (size_t)row * KD;
#pragma unroll
    for (int ks = 0; ks < NK32; ++ks) {
        int k0 = ks * 32 + q * 8;
        float4 a = {0.f, 0.f, 0.f, 0.f}, b = {0.f, 0.f, 0.f, 0.f};
        if (rv && k0 < KD) {
            a = *(const float4*)(src + k0);
            b = *(const float4*)(src + k0 + 4);
        }
        *(short8*)(Wf + ((size_t)u * NK32 + ks) * 512 + lane * 8) = pack8(a, b);
    }
}

__device__ __forceinline__ void dev_transpose(int bx, int by,
                                              const float* __restrict__ src,
                                              unsigned short* __restrict__ dst,
                                              int K, int N) {
    __shared__ unsigned short tile[32][33];
    int k0 = by * 32, n0 = bx * 32;
    int tx = threadIdx.x & 31, ty = threadIdx.x >> 5;
#pragma unroll
    for (int j = 0; j < 4; ++j) {
        int k = k0 + ty + j * 8, n = n0 + tx;
        float v = (n < N) ? src[(size_t)k * N + n] : 0.f;
        tile[ty + j * 8][tx] = f2bf(v);
    }
    __syncthreads();
#pragma unroll
    for (int j = 0; j < 4; ++j) {
        int n = n0 + ty + j * 8, k = k0 + tx;
        if (n < N) dst[(size_t)n * K + k] = tile[tx][ty + j * 8];
    }
}

// prep block ranges: [0,1024) hidden | [1024,1337) W0 | [1337,1650) W1 |
// [1650,4150) W2 | [4150,5209) W3 | [5209,6233) T0 | [6233,6489) T1 |
// [6489,6553) T2 | [6553,6585) T3
__global__ __launch_bounds__(256)
void k_prep(const float* __restrict__ hidden, unsigned short* __restrict__ hid_bf,
            const float* __restrict__ W0, unsigned short* __restrict__ W0f,
            const float* __restrict__ W1, unsigned short* __restrict__ W1f,
            const float* __restrict__ W2, unsigned short* __restrict__ W2f,
            const float* __restrict__ W3, unsigned short* __restrict__ W3f,
            const float* __restrict__ proj0, unsigned short* __restrict__ pT0,
            const float* __restrict__ proj1, unsigned short* __restrict__ pT1,
            const float* __restrict__ proj2, unsigned short* __restrict__ pT2,
            const float* __restrict__ proj3, unsigned short* __restrict__ pT3) {
    int bid = blockIdx.x, tid = threadIdx.x;
    if (bid < 1024) {
        int i = bid * 256 + tid;   // n4 = 262144 exactly
        float4 v = ((const float4*)hidden)[i];
        ushort4 o;
        o.x = f2bf(v.x); o.y = f2bf(v.y); o.z = f2bf(v.z); o.w = f2bf(v.w);
        ((ushort4*)hid_bf)[i] = o;
    }
    else if (bid < 1337) dev_convw<32, 1024>(bid - 1024, W0, W0f, 20000, 1250);
    else if (bid < 1650) dev_convw<8,  256> (bid - 1337, W1, W1f, 20000, 1250);
    else if (bid < 4150) dev_convw<2,  64>  (bid - 1650, W2, W2f, 160000, 10000);
    else if (bid < 5209) dev_convw<1,  16>  (bid - 4150, W3, W3f, 67735, 4234);
    else if (bid < 6233) { int i = bid - 5209; dev_transpose(i & 31, i >> 5, proj0, pT0, 1024, 1024); }
    else if (bid < 6489) { int i = bid - 6233; dev_transpose(i & 7,  i >> 3, proj1, pT1, 1024, 256); }
    else if (bid < 6553) { int i = bid - 6489; dev_transpose(i & 1,  i >> 1, proj2, pT2, 1024, 64); }
    else                 { int i = bid - 6553; dev_transpose(0,      i,      proj3, pT3, 1024, 16); }
}

// ================= projection GEMM (frag-major out) =================
#define BM 128
#define BN 128
#define BK 64
#define LDT 72
template <int NK32O>
__device__ __forceinline__ void dev_gemm(unsigned short* __restrict__ ls,
                                         int bx, int by,
                                         const unsigned short* __restrict__ A, int lda,
                                         const unsigned short* __restrict__ B, int ldb,
                                         unsigned short* __restrict__ Cf,
                                         int N, int K) {
    unsigned short* lsA = ls;
    unsigned short* lsB = ls + BM * LDT;
    int tid = threadIdx.x;
    int mBase = bx * BM, nBase = by * BN;
    int wid = tid >> 6, lane = tid & 63;
    int wr = wid >> 1, wc = wid & 1;
    int q = lane >> 4, ln = lane & 15;
    f32x4 acc[4][4] = {};

    for (int k0 = 0; k0 < K; k0 += BK) {
        __syncthreads();
        int ch = tid & 7;
#pragma unroll
        for (int p = 0; p < 4; ++p) {
            int r = p * 32 + (tid >> 3);
            *(uint4*)(&lsA[r * LDT + ch * 8]) =
                *(const uint4*)(A + (size_t)(mBase + r) * lda + k0 + ch * 8);
        }
#pragma unroll
        for (int p = 0; p < 4; ++p) {
            int r = p * 32 + (tid >> 3);
            uint4 v = {0u, 0u, 0u, 0u};
            if (nBase + r < N)
                v = *(const uint4*)(B + (size_t)(nBase + r) * ldb + k0 + ch * 8);
            *(uint4*)(&lsB[r * LDT + ch * 8]) = v;
        }
        __syncthreads();
#pragma unroll
        for (int ks = 0; ks < 2; ++ks) {
            short8 af[4], bfr[4];
#pragma unroll
            for (int mi = 0; mi < 4; ++mi)
                af[mi] = *(const short8*)(&lsA[(wr * 64 + mi * 16 + ln) * LDT + ks * 32 + q * 8]);
#pragma unroll
            for (int ni = 0; ni < 4; ++ni)
                bfr[ni] = *(const short8*)(&lsB[(wc * 64 + ni * 16 + ln) * LDT + ks * 32 + q * 8]);
#pragma unroll
            for (int mi = 0; mi < 4; ++mi)
#pragma unroll
                for (int ni = 0; ni < 4; ++ni)
                    acc[mi][ni] = __builtin_amdgcn_mfma_f32_16x16x32_bf16(
                        af[mi], bfr[ni], acc[mi][ni], 0, 0, 0);
        }
    }
#pragma unroll
    for (int ni = 0; ni < 4; ++ni) {
        int col = nBase + wc * 64 + ni * 16 + ln;
        if (col < N) {
            int k32 = col >> 5, qc = (col >> 3) & 3, j = col & 7;
#pragma unroll
            for (int mi = 0; mi < 4; ++mi) {
                int m16 = (mBase >> 4) + wr * 4 + mi;
                size_t base = ((size_t)m16 * NK32O + k32) * 512 + (size_t)qc * 128 + j;
#pragma unroll
                for (int r = 0; r < 4; ++r) {
                    int mrem = q * 4 + r;
                    Cf[base + mrem * 8] = f2bf(acc[mi][ni][r]);
                }
            }
        }
    }
}

// gemm ranges: [0,64) c0 | [64,80) c1 | [80,88) c2 | [88,96) c3
__global__ __launch_bounds__(256)
void k_gemm_all(const unsigned short* __restrict__ hid_bf,
                const unsigned short* __restrict__ pT0, const unsigned short* __restrict__ pT1,
                const unsigned short* __restrict__ pT2, const unsigned short* __restrict__ pT3,
                unsigned short* __restrict__ h0f, unsigned short* __restrict__ h1f,
                unsigned short* __restrict__ h2f, unsigned short* __restrict__ h3f) {
    __shared__ unsigned short ls[(BM + BN) * LDT];
    int bid = blockIdx.x;
    if (bid < 64)      dev_gemm<32>(ls, bid & 7, bid >> 3, hid_bf, 1024, pT0, 1024, h0f, 1024, 1024);
    else if (bid < 80) { int i = bid - 64; dev_gemm<8>(ls, i & 7, i >> 3, hid_bf, 1024, pT1, 1024, h1f, 256, 1024); }
    else if (bid < 88) dev_gemm<2>(ls, bid - 80, 0, hid_bf, 1024, pT2, 1024, h2f, 64, 1024);
    else               dev_gemm<1>(ls, bid - 88, 0, hid_bf, 1024, pT3, 1024, h3f, 16, 1024);
}

// ================= head: depth-3 pipelined frag streamer =================
__device__ __forceinline__ void dev_head(int f,
                const unsigned short* __restrict__ Af,   // h0f [64][32][64][8]
                const unsigned short* __restrict__ Wf,   // W0f [1250][32][64][8]
                const float* __restrict__ bias,
                float* __restrict__ rowsum, int vocab) {
    int u = f & 63;
    int xb = u >> 3;
    int yb = ((f >> 6) << 3) + (u & 7);   // same (u&7) => same XCD
    if (yb * 128 >= vocab) return;

    int tid = threadIdx.x, wid = tid >> 6, lane = tid & 63;
    int wr = wid >> 1, wc = wid & 1;
    int q = lane >> 4, ln = lane & 15;
    int mb = xb * 128 + wr * 64;
    int nb = yb * 128 + wc * 64;
    int units = (vocab + 15) >> 4;

    const unsigned short* Ab = Af + (size_t)(mb >> 4) * 32 * 512 + lane * 8;
    const unsigned short* Wp[4];
#pragma unroll
    for (int ni = 0; ni < 4; ++ni)
        Wp[ni] = Wf + (size_t)min((nb >> 4) + ni, units - 1) * 32 * 512 + lane * 8;

    f32x4 acc[4][4] = {};
    short8 Abf[3][4], Wbf[3][4];
    auto LA = [&](short8* d, int kk) {
#pragma unroll
        for (int mi = 0; mi < 4; ++mi)
            d[mi] = *(const short8*)(Ab + ((size_t)mi * 32 + kk) * 512);
    };
    auto LW = [&](short8* d, int kk) {
#pragma unroll
        for (int ni = 0; ni < 4; ++ni)
            d[ni] = *(const short8*)(Wp[ni] + (size_t)kk * 512);
    };
    auto FM = [&](short8* a, short8* w) {
#pragma unroll
        for (int mi = 0; mi < 4; ++mi)
#pragma unroll
            for (int ni = 0; ni < 4; ++ni)
                acc[mi][ni] = __builtin_amdgcn_mfma_f32_16x16x32_bf16(
                    a[mi], w[ni], acc[mi][ni], 0, 0, 0);
    };

    LA(Abf[0], 0); LW(Wbf[0], 0);
    LA(Abf[1], 1); LW(Wbf[1], 1);
#pragma unroll
    for (int ks = 0; ks < 32; ++ks) {
        int nxt = (ks + 2) % 3, cur = ks % 3;   // fully unrolled -> static
        if (ks + 2 < 32) { LA(Abf[nxt], ks + 2); LW(Wbf[nxt], ks + 2); }
        FM(Abf[cur], Wbf[cur]);
    }

    float s[4][4];
#pragma unroll
    for (int mi = 0; mi < 4; ++mi)
#pragma unroll
        for (int r = 0; r < 4; ++r) s[mi][r] = 0.f;
#pragma unroll
    for (int ni = 0; ni < 4; ++ni) {
        int col = nb + ni * 16 + ln;
        bool valid = col < vocab;
        float b = valid ? bias[col] : 0.f;
#pragma unroll
        for (int mi = 0; mi < 4; ++mi)
#pragma unroll
            for (int r = 0; r < 4; ++r)
                s[mi][r] += valid ? __expf(acc[mi][ni][r] + b) : 0.f;
    }
#pragma unroll
    for (int mi = 0; mi < 4; ++mi)
#pragma unroll
        for (int r = 0; r < 4; ++r) {
            float v = s[mi][r];
            v += __shfl_xor(v, 1, 64);
            v += __shfl_xor(v, 2, 64);
            v += __shfl_xor(v, 4, 64);
            v += __shfl_xor(v, 8, 64);
            s[mi][r] = v;
        }
    int sl = yb & 31;
    if (ln == 0) {
#pragma unroll
        for (int mi = 0; mi < 4; ++mi)
#pragma unroll
            for (int r = 0; r < 4; ++r)
                atomicAdd(&rowsum[sl * 1024 + mb + mi * 16 + q * 4 + r], s[mi][r]);
    }
}

// ================= tails: A-stationary streamers =================
template <int NK32>
__device__ __forceinline__ void dev_tail(int bx, int by,
                const unsigned short* __restrict__ Af,
                const unsigned short* __restrict__ Wf,
                const float* __restrict__ bias,
                float* __restrict__ rowsum,
                int vocab, int units, int ngroups) {
    int tid = threadIdx.x;
    int wid = tid >> 6, lane = tid & 63;
    int q = lane >> 4, ln = lane & 15;
    int m16b = by * 16 + wid * 4;
    int u0 = bx * ngroups;

    short8 af[4][NK32];
#pragma unroll
    for (int mi = 0; mi < 4; ++mi)
#pragma unroll
        for (int ks = 0; ks < NK32; ++ks)
            af[mi][ks] = *(const short8*)(Af + ((size_t)(m16b + mi) * NK32 + ks) * 512 + lane * 8);

    float rs[4][4];
#pragma unroll
    for (int mi = 0; mi < 4; ++mi)
#pragma unroll
        for (int r = 0; r < 4; ++r) rs[mi][r] = 0.f;

    const unsigned short* Wb = Wf + (size_t)lane * 8;
    auto LWG = [&](short8* d, int u) {
        int uc = min(u, units - 1);
#pragma unroll
        for (int ks = 0; ks < NK32; ++ks)
            d[ks] = *(const short8*)(Wb + ((size_t)uc * NK32 + ks) * 512);
    };
    auto CG = [&](short8* w, int u) {
        f32x4 acc[4] = {};
#pragma unroll
        for (int ks = 0; ks < NK32; ++ks)
#pragma unroll
            for (int mi = 0; mi < 4; ++mi)
                acc[mi] = __builtin_amdgcn_mfma_f32_16x16x32_bf16(
                    af[mi][ks], w[ks], acc[mi], 0, 0, 0);
        int col = u * 16 + ln;
        bool valid = col < vocab;
        float b = valid ? bias[col] : 0.f;
#pragma unroll
        for (int mi = 0; mi < 4; ++mi)
#pragma unroll
            for (int r = 0; r < 4; ++r)
                rs[mi][r] += valid ? __expf(acc[mi][r] + b) : 0.f;
    };

    short8 w0[NK32], w1[NK32];
    LWG(w0, u0);
    int g = 0;
    for (; g + 1 < ngroups; g += 2) {
        LWG(w1, u0 + g + 1);
        CG(w0, u0 + g);
        LWG(w0, u0 + g + 2);
        CG(w1, u0 + g + 1);
    }
    if (g < ngroups) CG(w0, u0 + g);

    int sl = bx & 31;
#pragma unroll
    for (int mi = 0; mi < 4; ++mi)
#pragma unroll
        for (int r = 0; r < 4; ++r) {
            float v = rs[mi][r];
            v += __shfl_xor(v, 1, 64);
            v += __shfl_xor(v, 2, 64);
            v += __shfl_xor(v, 4, 64);
            v += __shfl_xor(v, 8, 64);
            if (ln == 0)
                atomicAdd(&rowsum[sl * 1024 + (m16b + mi) * 16 + q * 4 + r], v);
        }
}

// ================= gather =================
__device__ __forceinline__ float frag_dot(const unsigned short* __restrict__ hf,
                                          int NK32, int KdReal, int n,
                                          const float* __restrict__ wrow, int lane) {
    float s = 0.f;
    for (int c = lane; c * 8 < KdReal; c += 64) {
        int k32 = c >> 2, qq = c & 3;
        const unsigned short* p = hf + ((size_t)(n >> 4) * NK32 + k32) * 512 + (qq * 16 + (n & 15)) * 8;
#pragma unroll
        for (int j = 0; j < 8; ++j)
            s += bf2f(p[j]) * wrow[c * 8 + j];
    }
    return wave_sum(s);
}

__device__ __forceinline__ void dev_gather(int bid,
                         const unsigned short* __restrict__ h0f,
                         const unsigned short* __restrict__ h1f,
                         const unsigned short* __restrict__ h2f,
                         const unsigned short* __restrict__ h3f,
                         const float* __restrict__ W0, const float* __restrict__ b0,
                         const float* __restrict__ W1, const float* __restrict__ b1,
                         const float* __restrict__ W2, const float* __restrict__ b2,
                         const float* __restrict__ W3, const float* __restrict__ b3,
                         const float* __restrict__ cW, const float* __restrict__ cb,
                         const int* __restrict__ target,
                         float* __restrict__ rowsum0,
                         float* __restrict__ gat_head,
                         float* __restrict__ gat_tail) {
    int gw = bid * 4 + (threadIdx.x >> 6);
    int lane = threadIdx.x & 63;
    if (gw >= 1024) return;
    int n = gw;
    int t = target[n];

    float cl[3];
#pragma unroll
    for (int j = 0; j < 3; ++j)
        cl[j] = frag_dot(h0f, 32, 1024, n, cW + j * 1024, lane) + cb[j];
    if (lane == 0)
        atomicAdd(&rowsum0[n], __expf(cl[0]) + __expf(cl[1]) + __expf(cl[2]));

    float gh, gt = 0.f;
    if (t < 20000) {
        gh = frag_dot(h0f, 32, 1024, n, W0 + (size_t)t * 1024, lane) + b0[t];
    } else {
        int c, l, Kd, NK32;
        const unsigned short* h; const float* W; const float* b;
        if (t < 40000)       { c = 1; l = 20000;  Kd = 256; NK32 = 8; h = h1f; W = W1; b = b1; }
        else if (t < 200000) { c = 2; l = 40000;  Kd = 64;  NK32 = 2; h = h2f; W = W2; b = b2; }
        else                 { c = 3; l = 200000; Kd = 16;  NK32 = 1; h = h3f; W = W3; b = b3; }
        gh = cl[3 - c];
        gt = frag_dot(h, NK32, Kd, n, W + (size_t)(t - l) * Kd, lane) + b[t - l];
    }
    if (lane == 0) { gat_head[n] = gh; gat_tail[n] = gt; }
}

// ================= mega logit launch =================
// [0,1280) head | [1280,1536) c1 | [1536,2176) c2 | [2176,2688) c3 |
// [2688,2944) gather.   All bases % 8 == 0; same-column blocks spaced
// by multiples of 8 -> share an XCD L2.
__global__ __launch_bounds__(256, 2)
void k_logit_all(const unsigned short* __restrict__ h0f, const unsigned short* __restrict__ h1f,
                 const unsigned short* __restrict__ h2f, const unsigned short* __restrict__ h3f,
                 const unsigned short* __restrict__ W0f, const unsigned short* __restrict__ W1f,
                 const unsigned short* __restrict__ W2f, const unsigned short* __restrict__ W3f,
                 const float* __restrict__ W0, const float* __restrict__ b0,
                 const float* __restrict__ W1, const float* __restrict__ b1,
                 const float* __restrict__ W2, const float* __restrict__ b2,
                 const float* __restrict__ W3, const float* __restrict__ b3,
                 const float* __restrict__ cW, const float* __restrict__ cb,
                 const int* __restrict__ target,
                 float* __restrict__ rowsum,
                 float* __restrict__ gat_head, float* __restrict__ gat_tail) {
    int bid = blockIdx.x;
    if (bid < 1280) {
        dev_head(bid, h0f, W0f, b0, rowsum, 20000);
    } else if (bid < 1536) {
        int i = bid - 1280;
        dev_tail<8>(i & 63, i >> 6, h1f, W1f, b1, rowsum + 32768, 20000, 1250, 20);
    } else if (bid < 2176) {
        int i = bid - 1536;
        dev_tail<2>(i % 160, i / 160, h2f, W2f, b2, rowsum + 65536, 160000, 10000, 63);
    } else if (bid < 2688) {
        int i = bid - 2176;
        dev_tail<1>(i & 127, i >> 7, h3f, W3f, b3, rowsum + 98304, 67735, 4234, 34);
    } else {
        dev_gather(bid - 2688, h0f, h1f, h2f, h3f, W0, b0, W1, b1, W2, b2, W3, b3,
                   cW, cb, target, rowsum, gat_head, gat_tail);
    }
}

// ================= finalize =================
__global__ void k_finalize(const float* __restrict__ rs,  // [4][32][1024]
                           const float* __restrict__ gat_head,
                           const float* __restrict__ gat_tail,
                           const int* __restrict__ target,
                           float* __restrict__ out) {
    __shared__ float red[16];
    int n = threadIdx.x;
    int t = target[n];
    float r0 = 0.f;
#pragma unroll
    for (int s = 0; s < 32; ++s) r0 += rs[s * 1024 + n];
    float nll = __logf(r0) - gat_head[n];
    int c = (t < 20000) ? 0 : (t < 40000) ? 1 : (t < 200000) ? 2 : 3;
    if (c > 0) {
        float rc = 0.f;
#pragma unroll
        for (int s = 0; s < 32; ++s) rc += rs[c * 32768 + s * 1024 + n];
        nll += __logf(rc) - gat_tail[n];
    }
    float sm = wave_sum(nll);
    int wid = n >> 6, lane = n & 63;
    if (lane == 0) red[wid] = sm;
    __syncthreads();
    if (n == 0) {
        float tot = 0.f;
#pragma unroll
        for (int i = 0; i < 16; ++i) tot += red[i];
        out[0] = tot / 1024.0f;
    }
}

// ============================================================
extern "C" void kernel_launch(void* const* d_in, const int* in_sizes, int n_in,
                              void* d_out, int out_size, void* d_ws, size_t ws_size,
                              hipStream_t stream) {
    const float* hidden = (const float*)d_in[0];
    const int*   target = (const int*)d_in[1];
    const float* W0 = (const float*)d_in[2];
    const float* b0 = (const float*)d_in[3];
    const float* proj0 = (const float*)d_in[4];
    const float* W1 = (const float*)d_in[5];
    const float* b1 = (const float*)d_in[6];
    const float* proj1 = (const float*)d_in[7];
    const float* W2 = (const float*)d_in[8];
    const float* b2 = (const float*)d_in[9];
    const float* proj2 = (const float*)d_in[10];
    const float* W3 = (const float*)d_in[11];
    const float* b3 = (const float*)d_in[12];
    const float* proj3 = (const float*)d_in[13];
    const float* cW = (const float*)d_in[14];
    const float* cb = (const float*)d_in[15];

    char* ws = (char*)d_ws;
    unsigned short* hid_bf = (unsigned short*)(ws + 0x000000);  // 2 MB row-major bf16
    unsigned short* pT0 = (unsigned short*)(ws + 0x200000);     // 2 MB
    unsigned short* pT1 = (unsigned short*)(ws + 0x400000);     // 512 KB
    unsigned short* pT2 = (unsigned short*)(ws + 0x480000);     // 128 KB
    unsigned short* pT3 = (unsigned short*)(ws + 0x4A0000);     // 32 KB
    unsigned short* h0f = (unsigned short*)(ws + 0x4A8000);     // 2 MB   frag [64][32][64][8]
    unsigned short* h1f = (unsigned short*)(ws + 0x6A8000);     // 512 KB frag [64][8][64][8]
    unsigned short* h2f = (unsigned short*)(ws + 0x728000);     // 128 KB frag [64][2][64][8]
    unsigned short* h3f = (unsigned short*)(ws + 0x748000);     // 64 KB  frag [64][1][64][8] (K padded 16->32)
    float* rowsum   = (float*)(ws + 0x758000);                  // [4][32][1024] = 512 KB
    float* gat_head = (float*)(ws + 0x7D8000);                  // 4 KB
    float* gat_tail = (float*)(ws + 0x7D9000);                  // 4 KB
    unsigned short* W0f = (unsigned short*)(ws + 0x00800000);   // 40.96 MB
    unsigned short* W1f = (unsigned short*)(ws + 0x02F10000);   // 10.24 MB
    unsigned short* W2f = (unsigned short*)(ws + 0x038D4000);   // 20.48 MB
    unsigned short* W3f = (unsigned short*)(ws + 0x04C5C000);   //  4.34 MB

    hipMemsetAsync(ws + 0x748000, 0, 0x92000, stream);

    k_prep<<<6585, 256, 0, stream>>>(hidden, hid_bf, W0, W0f, W1, W1f, W2, W2f, W3, W3f,
                                     proj0, pT0, proj1, pT1, proj2, pT2, proj3, pT3);

    k_gemm_all<<<96, 256, 0, stream>>>(hid_bf, pT0, pT1, pT2, pT3, h0f, h1f, h2f, h3f);

    k_logit_all<<<2944, 256, 0, stream>>>(h0f, h1f, h2f, h3f, W0f, W1f, W2f, W3f,
                                          W0, b0, W1, b1, W2, b2, W3, b3,
                                          cW, cb, target, rowsum, gat_head, gat_tail);

    k_finalize<<<1, 1024, 0, stream>>>(rowsum, gat_head, gat_tail, target, (float*)d_out);
}

// Round 5
// 395.408 us; speedup vs baseline: 1.7614x; 1.0440x over previous
//
#include <hip/hip_runtime.h>
#include <stdint.h>

// ============================================================
// Adaptive log-softmax NLL, MI355X gfx950.  Round 10.
// R9 counters: logit_all 157us (VGPR 116 -> tail<8>'s 128-reg af[]
// poisoned regalloc; VALU 37% = per-logit masking on 275M logits);
// ~255us invisible in prep/gemm serialization.
// Fixes:
//  (1) c1 -> head-style dual-stream (kills the 128-VGPR branch).
//  (2) bias-padding: Wf zero-padded to full col-groups + padded bias
//      arrays with -1e30 -> exp()=0 for pads; ALL masks/clamps deleted
//      from hot loops.
//  (3) launch repack: pre {hidden conv, transposes, bias pads} ->
//      mid {gemm blocks first + W converts backfill} -> logit -> final.
// ============================================================

typedef __attribute__((ext_vector_type(8))) short short8;   // 8 bf16
typedef __attribute__((ext_vector_type(4))) float f32x4;

__device__ __forceinline__ float bf2f(unsigned short u) {
    union { unsigned int i; float f; } v; v.i = ((unsigned int)u) << 16; return v.f;
}
__device__ __forceinline__ unsigned short f2bf(float f) {
    union { float f; unsigned int i; } v; v.f = f;
    unsigned int u = v.i;
    return (unsigned short)((u + 0x7fffu + ((u >> 16) & 1u)) >> 16);  // RNE
}
__device__ __forceinline__ float wave_sum(float v) {
    v += __shfl_xor(v, 1, 64);  v += __shfl_xor(v, 2, 64);
    v += __shfl_xor(v, 4, 64);  v += __shfl_xor(v, 8, 64);
    v += __shfl_xor(v, 16, 64); v += __shfl_xor(v, 32, 64);
    return v;
}
__device__ __forceinline__ short8 pack8(float4 a, float4 b) {
    union { int4 i; short8 s; } r;
    r.i.x = __builtin_amdgcn_perm(__float_as_uint(a.y), __float_as_uint(a.x), 0x07060302u);
    r.i.y = __builtin_amdgcn_perm(__float_as_uint(a.w), __float_as_uint(a.z), 0x07060302u);
    r.i.z = __builtin_amdgcn_perm(__float_as_uint(b.y), __float_as_uint(b.x), 0x07060302u);
    r.i.w = __builtin_amdgcn_perm(__float_as_uint(b.w), __float_as_uint(b.z), 0x07060302u);
    return r.s;
}

// ================= pre: transpose =================
__device__ __forceinline__ void dev_transpose(int bx, int by,
                                              const float* __restrict__ src,
                                              unsigned short* __restrict__ dst,
                                              int K, int N) {
    __shared__ unsigned short tile[32][33];
    int k0 = by * 32, n0 = bx * 32;
    int tx = threadIdx.x & 31, ty = threadIdx.x >> 5;
#pragma unroll
    for (int j = 0; j < 4; ++j) {
        int k = k0 + ty + j * 8, n = n0 + tx;
        float v = (n < N) ? src[(size_t)k * N + n] : 0.f;
        tile[ty + j * 8][tx] = f2bf(v);
    }
    __syncthreads();
#pragma unroll
    for (int j = 0; j < 4; ++j) {
        int n = n0 + ty + j * 8, k = k0 + tx;
        if (n < N) dst[(size_t)n * K + k] = tile[tx][ty + j * 8];
    }
}

__device__ __forceinline__ void dev_biasfill(int bid, const float* __restrict__ b,
                                             float* __restrict__ bp, int vocab, int padded) {
    int i = bid * 256 + threadIdx.x;
    if (i < padded) bp[i] = (i < vocab) ? b[i] : -1e30f;
}

// pre ranges: [0,1024) hidden | [1024,2048) T0 | [2048,2304) T1 |
// [2304,2368) T2 | [2368,2400) T3 | [2400,2479) b0p | [2479,2558) b1p |
// [2558,3188) b2p | [3188,3460) b3p
__global__ __launch_bounds__(256)
void k_pre(const float* __restrict__ hidden, unsigned short* __restrict__ hid_bf,
           const float* __restrict__ proj0, unsigned short* __restrict__ pT0,
           const float* __restrict__ proj1, unsigned short* __restrict__ pT1,
           const float* __restrict__ proj2, unsigned short* __restrict__ pT2,
           const float* __restrict__ proj3, unsigned short* __restrict__ pT3,
           const float* __restrict__ b0, float* __restrict__ b0p,
           const float* __restrict__ b1, float* __restrict__ b1p,
           const float* __restrict__ b2, float* __restrict__ b2p,
           const float* __restrict__ b3, float* __restrict__ b3p) {
    int bid = blockIdx.x, tid = threadIdx.x;
    if (bid < 1024) {
        int i = bid * 256 + tid;   // 262144 float4 exactly
        float4 v = ((const float4*)hidden)[i];
        ushort4 o;
        o.x = f2bf(v.x); o.y = f2bf(v.y); o.z = f2bf(v.z); o.w = f2bf(v.w);
        ((ushort4*)hid_bf)[i] = o;
    }
    else if (bid < 2048) { int i = bid - 1024; dev_transpose(i & 31, i >> 5, proj0, pT0, 1024, 1024); }
    else if (bid < 2304) { int i = bid - 2048; dev_transpose(i & 7,  i >> 3, proj1, pT1, 1024, 256); }
    else if (bid < 2368) { int i = bid - 2304; dev_transpose(i & 1,  i >> 1, proj2, pT2, 1024, 64); }
    else if (bid < 2400) { int i = bid - 2368; dev_transpose(0,      i,      proj3, pT3, 1024, 16); }
    else if (bid < 2479) dev_biasfill(bid - 2400, b0, b0p, 20000, 20096);
    else if (bid < 2558) dev_biasfill(bid - 2479, b1, b1p, 20000, 20096);
    else if (bid < 3188) dev_biasfill(bid - 2558, b2, b2p, 160000, 161280);
    else                 dev_biasfill(bid - 3188, b3, b3p, 67735, 69632);
}

// ================= mid: W convert + projection GEMM =================
template <int NK32, int KD>
__device__ __forceinline__ void dev_convw(int bid, const float* __restrict__ W,
                                          unsigned short* __restrict__ Wf,
                                          int vocab, int upad) {
    int u = bid * 4 + (threadIdx.x >> 6);
    if (u >= upad) return;
    int lane = threadIdx.x & 63, q = lane >> 4, ln = lane & 15;
    int row = u * 16 + ln;
    bool rv = row < vocab;
    const float* src = W + (size_t)row * KD;
#pragma unroll
    for (int ks = 0; ks < NK32; ++ks) {
        int k0 = ks * 32 + q * 8;
        float4 a = {0.f, 0.f, 0.f, 0.f}, b = {0.f, 0.f, 0.f, 0.f};
        if (rv && k0 < KD) {
            a = *(const float4*)(src + k0);
            b = *(const float4*)(src + k0 + 4);
        }
        *(short8*)(Wf + ((size_t)u * NK32 + ks) * 512 + lane * 8) = pack8(a, b);
    }
}

#define BM 128
#define BN 128
#define BK 64
#define LDT 72
template <int NK32O>
__device__ __forceinline__ void dev_gemm(unsigned short* __restrict__ ls,
                                         int bx, int by,
                                         const unsigned short* __restrict__ A, int lda,
                                         const unsigned short* __restrict__ B, int ldb,
                                         unsigned short* __restrict__ Cf,
                                         int N, int K) {
    unsigned short* lsA = ls;
    unsigned short* lsB = ls + BM * LDT;
    int tid = threadIdx.x;
    int mBase = bx * BM, nBase = by * BN;
    int wid = tid >> 6, lane = tid & 63;
    int wr = wid >> 1, wc = wid & 1;
    int q = lane >> 4, ln = lane & 15;
    f32x4 acc[4][4] = {};

    for (int k0 = 0; k0 < K; k0 += BK) {
        __syncthreads();
        int ch = tid & 7;
#pragma unroll
        for (int p = 0; p < 4; ++p) {
            int r = p * 32 + (tid >> 3);
            *(uint4*)(&lsA[r * LDT + ch * 8]) =
                *(const uint4*)(A + (size_t)(mBase + r) * lda + k0 + ch * 8);
        }
#pragma unroll
        for (int p = 0; p < 4; ++p) {
            int r = p * 32 + (tid >> 3);
            uint4 v = {0u, 0u, 0u, 0u};
            if (nBase + r < N)
                v = *(const uint4*)(B + (size_t)(nBase + r) * ldb + k0 + ch * 8);
            *(uint4*)(&lsB[r * LDT + ch * 8]) = v;
        }
        __syncthreads();
#pragma unroll
        for (int ks = 0; ks < 2; ++ks) {
            short8 af[4], bfr[4];
#pragma unroll
            for (int mi = 0; mi < 4; ++mi)
                af[mi] = *(const short8*)(&lsA[(wr * 64 + mi * 16 + ln) * LDT + ks * 32 + q * 8]);
#pragma unroll
            for (int ni = 0; ni < 4; ++ni)
                bfr[ni] = *(const short8*)(&lsB[(wc * 64 + ni * 16 + ln) * LDT + ks * 32 + q * 8]);
#pragma unroll
            for (int mi = 0; mi < 4; ++mi)
#pragma unroll
                for (int ni = 0; ni < 4; ++ni)
                    acc[mi][ni] = __builtin_amdgcn_mfma_f32_16x16x32_bf16(
                        af[mi], bfr[ni], acc[mi][ni], 0, 0, 0);
        }
    }
#pragma unroll
    for (int ni = 0; ni < 4; ++ni) {
        int col = nBase + wc * 64 + ni * 16 + ln;
        if (col < N) {
            int k32 = col >> 5, qc = (col >> 3) & 3, j = col & 7;
#pragma unroll
            for (int mi = 0; mi < 4; ++mi) {
                int m16 = (mBase >> 4) + wr * 4 + mi;
                size_t base = ((size_t)m16 * NK32O + k32) * 512 + (size_t)qc * 128 + j;
#pragma unroll
                for (int r = 0; r < 4; ++r) {
                    int mrem = q * 4 + r;
                    Cf[base + mrem * 8] = f2bf(acc[mi][ni][r]);
                }
            }
        }
    }
}

// mid ranges: [0,96) gemm | [96,410) W0 | [410,724) W1 | [724,3244) W2 |
// [3244,4332) W3.  Gemm first so the 96 latency-bound blocks start at
// t=0; converts (BW-bound) backfill the other CUs.
__global__ __launch_bounds__(256)
void k_mid(const unsigned short* __restrict__ hid_bf,
           const unsigned short* __restrict__ pT0, const unsigned short* __restrict__ pT1,
           const unsigned short* __restrict__ pT2, const unsigned short* __restrict__ pT3,
           unsigned short* __restrict__ h0f, unsigned short* __restrict__ h1f,
           unsigned short* __restrict__ h2f, unsigned short* __restrict__ h3f,
           const float* __restrict__ W0, unsigned short* __restrict__ W0f,
           const float* __restrict__ W1, unsigned short* __restrict__ W1f,
           const float* __restrict__ W2, unsigned short* __restrict__ W2f,
           const float* __restrict__ W3, unsigned short* __restrict__ W3f) {
    __shared__ unsigned short ls[(BM + BN) * LDT];
    int bid = blockIdx.x;
    if (bid < 64)        dev_gemm<32>(ls, bid & 7, bid >> 3, hid_bf, 1024, pT0, 1024, h0f, 1024, 1024);
    else if (bid < 80)   { int i = bid - 64; dev_gemm<8>(ls, i & 7, i >> 3, hid_bf, 1024, pT1, 1024, h1f, 256, 1024); }
    else if (bid < 88)   dev_gemm<2>(ls, bid - 80, 0, hid_bf, 1024, pT2, 1024, h2f, 64, 1024);
    else if (bid < 96)   dev_gemm<1>(ls, bid - 88, 0, hid_bf, 1024, pT3, 1024, h3f, 16, 1024);
    else if (bid < 410)  dev_convw<32, 1024>(bid - 96,   W0, W0f, 20000, 1256);
    else if (bid < 724)  dev_convw<8,  256> (bid - 410,  W1, W1f, 20000, 1256);
    else if (bid < 3244) dev_convw<2,  64>  (bid - 724,  W2, W2f, 160000, 10080);
    else                 dev_convw<1,  16>  (bid - 3244, W3, W3f, 67735, 4352);
}

// ================= logit: dual-stream (c0, c1) =================
// 8 M-tiles x 160 col-groups (157 real), XCD-swizzled.  Depth-2 reg
// pipeline.  No masks: Wf pad units are zeros, biasp pads are -1e30.
template <int NK32>
__device__ __forceinline__ void dev_stream(int f,
                const unsigned short* __restrict__ Af,
                const unsigned short* __restrict__ Wf,
                const float* __restrict__ biasp,
                float* __restrict__ rowsum) {
    int u = f & 63;
    int xb = u >> 3;
    int yb = ((f >> 6) << 3) + (u & 7);   // same (u&7) => same XCD
    if (yb >= 157) return;

    int tid = threadIdx.x, wid = tid >> 6, lane = tid & 63;
    int wr = wid >> 1, wc = wid & 1;
    int q = lane >> 4, ln = lane & 15;
    int mb = xb * 128 + wr * 64;
    int nb = yb * 128 + wc * 64;

    const unsigned short* Ab = Af + (size_t)(mb >> 4) * NK32 * 512 + lane * 8;
    const unsigned short* Wp[4];
#pragma unroll
    for (int ni = 0; ni < 4; ++ni)
        Wp[ni] = Wf + (size_t)((nb >> 4) + ni) * NK32 * 512 + lane * 8;

    f32x4 acc[4][4] = {};
    short8 a0[4], a1[4], w0[4], w1[4];
    auto LA = [&](short8* d, int kk) {
#pragma unroll
        for (int mi = 0; mi < 4; ++mi)
            d[mi] = *(const short8*)(Ab + ((size_t)mi * NK32 + kk) * 512);
    };
    auto LW = [&](short8* d, int kk) {
#pragma unroll
        for (int ni = 0; ni < 4; ++ni)
            d[ni] = *(const short8*)(Wp[ni] + (size_t)kk * 512);
    };
    auto FM = [&](short8* a, short8* w) {
#pragma unroll
        for (int mi = 0; mi < 4; ++mi)
#pragma unroll
            for (int ni = 0; ni < 4; ++ni)
                acc[mi][ni] = __builtin_amdgcn_mfma_f32_16x16x32_bf16(
                    a[mi], w[ni], acc[mi][ni], 0, 0, 0);
    };

    LA(a0, 0); LW(w0, 0);
#pragma unroll
    for (int ks = 0; ks < NK32; ks += 2) {
        LA(a1, ks + 1); LW(w1, ks + 1);
        FM(a0, w0);
        if (ks + 2 < NK32) { LA(a0, ks + 2); LW(w0, ks + 2); }
        FM(a1, w1);
    }

    float s[4][4];
#pragma unroll
    for (int mi = 0; mi < 4; ++mi)
#pragma unroll
        for (int r = 0; r < 4; ++r) s[mi][r] = 0.f;
#pragma unroll
    for (int ni = 0; ni < 4; ++ni) {
        float b = biasp[nb + ni * 16 + ln];
#pragma unroll
        for (int mi = 0; mi < 4; ++mi)
#pragma unroll
            for (int r = 0; r < 4; ++r)
                s[mi][r] += __expf(acc[mi][ni][r] + b);
    }
#pragma unroll
    for (int mi = 0; mi < 4; ++mi)
#pragma unroll
        for (int r = 0; r < 4; ++r) {
            float v = s[mi][r];
            v += __shfl_xor(v, 1, 64);
            v += __shfl_xor(v, 2, 64);
            v += __shfl_xor(v, 4, 64);
            v += __shfl_xor(v, 8, 64);
            s[mi][r] = v;
        }
    int sl = yb & 31;
    if (ln == 0) {
#pragma unroll
        for (int mi = 0; mi < 4; ++mi)
#pragma unroll
            for (int r = 0; r < 4; ++r)
                atomicAdd(&rowsum[sl * 1024 + mb + mi * 16 + q * 4 + r], s[mi][r]);
    }
}

// ================= logit: A-stationary tails (c2, c3) =================
template <int NK32>
__device__ __forceinline__ void dev_tail(int bx, int by,
                const unsigned short* __restrict__ Af,
                const unsigned short* __restrict__ Wf,
                const float* __restrict__ biasp,
                float* __restrict__ rowsum, int ngroups) {
    int tid = threadIdx.x;
    int wid = tid >> 6, lane = tid & 63;
    int q = lane >> 4, ln = lane & 15;
    int m16b = by * 16 + wid * 4;
    int u0 = bx * ngroups;

    short8 af[4][NK32];
#pragma unroll
    for (int mi = 0; mi < 4; ++mi)
#pragma unroll
        for (int ks = 0; ks < NK32; ++ks)
            af[mi][ks] = *(const short8*)(Af + ((size_t)(m16b + mi) * NK32 + ks) * 512 + lane * 8);

    float rs[4][4];
#pragma unroll
    for (int mi = 0; mi < 4; ++mi)
#pragma unroll
        for (int r = 0; r < 4; ++r) rs[mi][r] = 0.f;

    const unsigned short* Wb = Wf + (size_t)lane * 8;
    auto LWG = [&](short8* d, int u) {
#pragma unroll
        for (int ks = 0; ks < NK32; ++ks)
            d[ks] = *(const short8*)(Wb + ((size_t)u * NK32 + ks) * 512);
    };
    auto CG = [&](short8* w, int u) {
        f32x4 acc[4] = {};
#pragma unroll
        for (int ks = 0; ks < NK32; ++ks)
#pragma unroll
            for (int mi = 0; mi < 4; ++mi)
                acc[mi] = __builtin_amdgcn_mfma_f32_16x16x32_bf16(
                    af[mi][ks], w[ks], acc[mi], 0, 0, 0);
        float b = biasp[u * 16 + ln];
#pragma unroll
        for (int mi = 0; mi < 4; ++mi)
#pragma unroll
            for (int r = 0; r < 4; ++r)
                rs[mi][r] += __expf(acc[mi][r] + b);
    };

    short8 w0[NK32], w1[NK32];
    LWG(w0, u0);
    int g = 0;
    for (; g + 1 < ngroups; g += 2) {
        LWG(w1, u0 + g + 1);
        CG(w0, u0 + g);
        LWG(w0, u0 + g + 2);
        CG(w1, u0 + g + 1);
    }
    if (g < ngroups) CG(w0, u0 + g);

    int sl = bx & 31;
#pragma unroll
    for (int mi = 0; mi < 4; ++mi)
#pragma unroll
        for (int r = 0; r < 4; ++r) {
            float v = rs[mi][r];
            v += __shfl_xor(v, 1, 64);
            v += __shfl_xor(v, 2, 64);
            v += __shfl_xor(v, 4, 64);
            v += __shfl_xor(v, 8, 64);
            if (ln == 0)
                atomicAdd(&rowsum[sl * 1024 + (m16b + mi) * 16 + q * 4 + r], v);
        }
}

// ================= gather =================
__device__ __forceinline__ float frag_dot(const unsigned short* __restrict__ hf,
                                          int NK32, int KdReal, int n,
                                          const float* __restrict__ wrow, int lane) {
    float s = 0.f;
    for (int c = lane; c * 8 < KdReal; c += 64) {
        int k32 = c >> 2, qq = c & 3;
        const unsigned short* p = hf + ((size_t)(n >> 4) * NK32 + k32) * 512 + (qq * 16 + (n & 15)) * 8;
#pragma unroll
        for (int j = 0; j < 8; ++j)
            s += bf2f(p[j]) * wrow[c * 8 + j];
    }
    return wave_sum(s);
}

__device__ __forceinline__ void dev_gather(int bid,
                         const unsigned short* __restrict__ h0f,
                         const unsigned short* __restrict__ h1f,
                         const unsigned short* __restrict__ h2f,
                         const unsigned short* __restrict__ h3f,
                         const float* __restrict__ W0, const float* __restrict__ b0,
                         const float* __restrict__ W1, const float* __restrict__ b1,
                         const float* __restrict__ W2, const float* __restrict__ b2,
                         const float* __restrict__ W3, const float* __restrict__ b3,
                         const float* __restrict__ cW, const float* __restrict__ cb,
                         const int* __restrict__ target,
                         float* __restrict__ rowsum0,
                         float* __restrict__ gat_head,
                         float* __restrict__ gat_tail) {
    int gw = bid * 4 + (threadIdx.x >> 6);
    int lane = threadIdx.x & 63;
    if (gw >= 1024) return;
    int n = gw;
    int t = target[n];

    float cl[3];
#pragma unroll
    for (int j = 0; j < 3; ++j)
        cl[j] = frag_dot(h0f, 32, 1024, n, cW + j * 1024, lane) + cb[j];
    if (lane == 0)
        atomicAdd(&rowsum0[n], __expf(cl[0]) + __expf(cl[1]) + __expf(cl[2]));

    float gh, gt = 0.f;
    if (t < 20000) {
        gh = frag_dot(h0f, 32, 1024, n, W0 + (size_t)t * 1024, lane) + b0[t];
    } else {
        int c, l, Kd, NK32;
        const unsigned short* h; const float* W; const float* b;
        if (t < 40000)       { c = 1; l = 20000;  Kd = 256; NK32 = 8; h = h1f; W = W1; b = b1; }
        else if (t < 200000) { c = 2; l = 40000;  Kd = 64;  NK32 = 2; h = h2f; W = W2; b = b2; }
        else                 { c = 3; l = 200000; Kd = 16;  NK32 = 1; h = h3f; W = W3; b = b3; }
        gh = cl[3 - c];
        gt = frag_dot(h, NK32, Kd, n, W + (size_t)(t - l) * Kd, lane) + b[t - l];
    }
    if (lane == 0) { gat_head[n] = gh; gat_tail[n] = gt; }
}

// ================= mega logit launch =================
// [0,1280) head | [1280,2560) c1 | [2560,3200) c2 | [3200,3712) c3 |
// [3712,3968) gather.
__global__ __launch_bounds__(256, 2)
void k_logit_all(const unsigned short* __restrict__ h0f, const unsigned short* __restrict__ h1f,
                 const unsigned short* __restrict__ h2f, const unsigned short* __restrict__ h3f,
                 const unsigned short* __restrict__ W0f, const unsigned short* __restrict__ W1f,
                 const unsigned short* __restrict__ W2f, const unsigned short* __restrict__ W3f,
                 const float* __restrict__ b0p, const float* __restrict__ b1p,
                 const float* __restrict__ b2p, const float* __restrict__ b3p,
                 const float* __restrict__ W0, const float* __restrict__ b0,
                 const float* __restrict__ W1, const float* __restrict__ b1,
                 const float* __restrict__ W2, const float* __restrict__ b2,
                 const float* __restrict__ W3, const float* __restrict__ b3,
                 const float* __restrict__ cW, const float* __restrict__ cb,
                 const int* __restrict__ target,
                 float* __restrict__ rowsum,
                 float* __restrict__ gat_head, float* __restrict__ gat_tail) {
    int bid = blockIdx.x;
    if (bid < 1280) {
        dev_stream<32>(bid, h0f, W0f, b0p, rowsum);
    } else if (bid < 2560) {
        dev_stream<8>(bid - 1280, h1f, W1f, b1p, rowsum + 32768);
    } else if (bid < 3200) {
        int i = bid - 2560;
        dev_tail<2>(i % 160, i / 160, h2f, W2f, b2p, rowsum + 65536, 63);
    } else if (bid < 3712) {
        int i = bid - 3200;
        dev_tail<1>(i & 127, i >> 7, h3f, W3f, b3p, rowsum + 98304, 34);
    } else {
        dev_gather(bid - 3712, h0f, h1f, h2f, h3f, W0, b0, W1, b1, W2, b2, W3, b3,
                   cW, cb, target, rowsum, gat_head, gat_tail);
    }
}

// ================= finalize =================
__global__ void k_finalize(const float* __restrict__ rs,  // [4][32][1024]
                           const float* __restrict__ gat_head,
                           const float* __restrict__ gat_tail,
                           const int* __restrict__ target,
                           float* __restrict__ out) {
    __shared__ float red[16];
    int n = threadIdx.x;
    int t = target[n];
    float r0 = 0.f;
#pragma unroll
    for (int s = 0; s < 32; ++s) r0 += rs[s * 1024 + n];
    float nll = __logf(r0) - gat_head[n];
    int c = (t < 20000) ? 0 : (t < 40000) ? 1 : (t < 200000) ? 2 : 3;
    if (c > 0) {
        float rc = 0.f;
#pragma unroll
        for (int s = 0; s < 32; ++s) rc += rs[c * 32768 + s * 1024 + n];
        nll += __logf(rc) - gat_tail[n];
    }
    float sm = wave_sum(nll);
    int wid = n >> 6, lane = n & 63;
    if (lane == 0) red[wid] = sm;
    __syncthreads();
    if (n == 0) {
        float tot = 0.f;
#pragma unroll
        for (int i = 0; i < 16; ++i) tot += red[i];
        out[0] = tot / 1024.0f;
    }
}

// ============================================================
extern "C" void kernel_launch(void* const* d_in, const int* in_sizes, int n_in,
                              void* d_out, int out_size, void* d_ws, size_t ws_size,
                              hipStream_t stream) {
    const float* hidden = (const float*)d_in[0];
    const int*   target = (const int*)d_in[1];
    const float* W0 = (const float*)d_in[2];
    const float* b0 = (const float*)d_in[3];
    const float* proj0 = (const float*)d_in[4];
    const float* W1 = (const float*)d_in[5];
    const float* b1 = (const float*)d_in[6];
    const float* proj1 = (const float*)d_in[7];
    const float* W2 = (const float*)d_in[8];
    const float* b2 = (const float*)d_in[9];
    const float* proj2 = (const float*)d_in[10];
    const float* W3 = (const float*)d_in[11];
    const float* b3 = (const float*)d_in[12];
    const float* proj3 = (const float*)d_in[13];
    const float* cW = (const float*)d_in[14];
    const float* cb = (const float*)d_in[15];

    char* ws = (char*)d_ws;
    unsigned short* hid_bf = (unsigned short*)(ws + 0x000000);  // 2 MB
    unsigned short* pT0 = (unsigned short*)(ws + 0x200000);     // 2 MB
    unsigned short* pT1 = (unsigned short*)(ws + 0x400000);     // 512 KB
    unsigned short* pT2 = (unsigned short*)(ws + 0x480000);     // 128 KB
    unsigned short* pT3 = (unsigned short*)(ws + 0x4A0000);     // 32 KB
    unsigned short* h0f = (unsigned short*)(ws + 0x4A8000);     // 2 MB
    unsigned short* h1f = (unsigned short*)(ws + 0x6A8000);     // 512 KB
    unsigned short* h2f = (unsigned short*)(ws + 0x728000);     // 128 KB
    unsigned short* h3f = (unsigned short*)(ws + 0x748000);     // 64 KB (K padded 16->32)
    float* rowsum   = (float*)(ws + 0x758000);                  // [4][32][1024] = 512 KB
    float* gat_head = (float*)(ws + 0x7D8000);                  // 4 KB
    float* gat_tail = (float*)(ws + 0x7D9000);                  // 4 KB
    unsigned short* W0f = (unsigned short*)(ws + 0x00800000);   // 1256u*32*1024B = 41.2 MB
    unsigned short* W1f = (unsigned short*)(ws + 0x02F40000);   // 1256u*8*1024B  = 10.3 MB
    unsigned short* W2f = (unsigned short*)(ws + 0x03910000);   // 10080u*2*1024B = 20.6 MB
    unsigned short* W3f = (unsigned short*)(ws + 0x04CC0000);   // 4352u*1*1024B  =  4.5 MB
    float* b0p = (float*)(ws + 0x05100000);                     // 20096 f
    float* b1p = (float*)(ws + 0x05114000);                     // 20096 f
    float* b2p = (float*)(ws + 0x05128000);                     // 161280 f
    float* b3p = (float*)(ws + 0x051C8000);                     // 69632 f -> end 0x520C000

    hipMemsetAsync(ws + 0x748000, 0, 0x92000, stream);

    k_pre<<<3460, 256, 0, stream>>>(hidden, hid_bf,
                                    proj0, pT0, proj1, pT1, proj2, pT2, proj3, pT3,
                                    b0, b0p, b1, b1p, b2, b2p, b3, b3p);

    k_mid<<<4332, 256, 0, stream>>>(hid_bf, pT0, pT1, pT2, pT3, h0f, h1f, h2f, h3f,
                                    W0, W0f, W1, W1f, W2, W2f, W3, W3f);

    k_logit_all<<<3968, 256, 0, stream>>>(h0f, h1f, h2f, h3f, W0f, W1f, W2f, W3f,
                                          b0p, b1p, b2p, b3p,
                                          W0, b0, W1, b1, W2, b2, W3, b3,
                                          cW, cb, target, rowsum, gat_head, gat_tail);

    k_finalize<<<1, 1024, 0, stream>>>(rowsum, gat_head, gat_tail, target, (float*)d_out);
}